// Round 9
// baseline (1066.438 us; speedup 1.0000x reference)
//
#include <hip/hip_runtime.h>
#include <math.h>

#define NN 100000
#define NE 1600000
#define DIN 256
#define HD 64
#define OUTD 32
#define EMBD 128
#define SLOPE 0.2f
#define AST2 36
#define NT ((NN + 63) / 64)
#define SCHUNK 1024
#define SNBLK ((NN + SCHUNK - 1) / SCHUNK)   // 98

__device__ __forceinline__ float lrelu(float x) { return x > 0.f ? x : SLOPE * x; }

// ================= CSR build =================
__global__ void k_count(const int* __restrict__ dst, int* __restrict__ cnt) {
    int i = blockIdx.x * blockDim.x + threadIdx.x;
    if (i < NE) atomicAdd(&cnt[dst[i]], 1);
}

__global__ __launch_bounds__(256) void k_scan1(const int* __restrict__ cnt,
                                               int* __restrict__ rowptr,
                                               int* __restrict__ blksum) {
    __shared__ int ts[256];
    int base = blockIdx.x * SCHUNK + threadIdx.x * 4;
    int v0 = 0, v1 = 0, v2 = 0, v3 = 0;
    if (base < NN)     v0 = cnt[base];
    if (base + 1 < NN) v1 = cnt[base + 1];
    if (base + 2 < NN) v2 = cnt[base + 2];
    if (base + 3 < NN) v3 = cnt[base + 3];
    int s = v0 + v1 + v2 + v3;
    ts[threadIdx.x] = s;
    __syncthreads();
    for (int off = 1; off < 256; off <<= 1) {
        int w = (threadIdx.x >= off) ? ts[threadIdx.x - off] : 0;
        __syncthreads();
        ts[threadIdx.x] += w;
        __syncthreads();
    }
    int excl = ts[threadIdx.x] - s;
    if (base < NN)     rowptr[base]     = excl;
    if (base + 1 < NN) rowptr[base + 1] = excl + v0;
    if (base + 2 < NN) rowptr[base + 2] = excl + v0 + v1;
    if (base + 3 < NN) rowptr[base + 3] = excl + v0 + v1 + v2;
    if (threadIdx.x == 255) blksum[blockIdx.x] = ts[255];
}

__global__ __launch_bounds__(128) void k_scan2(int* __restrict__ blksum) {
    __shared__ int ts[128];
    int t = threadIdx.x;
    int v = (t < SNBLK) ? blksum[t] : 0;
    ts[t] = v;
    __syncthreads();
    for (int off = 1; off < 128; off <<= 1) {
        int w = (t >= off) ? ts[t - off] : 0;
        __syncthreads();
        ts[t] += w;
        __syncthreads();
    }
    if (t < SNBLK) blksum[t] = ts[t] - v;
}

__global__ void k_scan3(const int* __restrict__ blksum, const int* __restrict__ cnt,
                        int* __restrict__ rowptr, int* __restrict__ cursor,
                        float* __restrict__ invdeg) {
    int i = blockIdx.x * blockDim.x + threadIdx.x;
    if (i < NN) {
        int v = rowptr[i] + blksum[i >> 10];
        rowptr[i] = v;
        cursor[i] = v;
        invdeg[i] = 1.0f / fmaxf((float)cnt[i], 1.0f);
    }
    if (i == 0) rowptr[NN] = NE;
}

__global__ void k_fill(const int* __restrict__ src, const int* __restrict__ dst,
                       int* __restrict__ cursor, int* __restrict__ colsrc) {
    int i = blockIdx.x * blockDim.x + threadIdx.x;
    if (i >= NE) return;
    int pos = atomicAdd(&cursor[dst[i]], 1);
    colsrc[pos] = src[i];
}

// ================= tiled GEMM helpers (K=32 chunks, reg-prefetch staging) =================
// A chunk: 64 rows x 32 cols -> 512 float4, 2 per thread
__device__ __forceinline__ void loadA32(const float* __restrict__ g, int nbase, int ldg,
                                        int koff, float4* r) {
#pragma unroll
    for (int u = 0; u < 2; u++) {
        int i = threadIdx.x + u * 256;
        int m = i >> 3, k4 = (i & 7) << 2;
        int row = nbase + m;
        if (row >= NN) row = NN - 1;
        r[u] = *(const float4*)&g[(size_t)row * ldg + koff + k4];
    }
}
__device__ __forceinline__ void writeA32(const float4* r, float (*As)[AST2]) {
#pragma unroll
    for (int u = 0; u < 2; u++) {
        int i = threadIdx.x + u * 256;
        int m = i >> 3, k4 = (i & 7) << 2;
        *(float4*)&As[m][k4] = r[u];
    }
}
// W panel: 32x64 contiguous -> 512 float4 linear
__device__ __forceinline__ void loadW32(const float* __restrict__ g, float4* r) {
#pragma unroll
    for (int u = 0; u < 2; u++) r[u] = ((const float4*)g)[threadIdx.x + u * 256];
}
// W panel from row-major [32][ldg] cols [coff,coff+64): linear float4 index i = r*16+c4/4
__device__ __forceinline__ void loadW32cols(const float* __restrict__ g, int ldg, int coff,
                                            float4* r) {
#pragma unroll
    for (int u = 0; u < 2; u++) {
        int i = threadIdx.x + u * 256;
        int rr = i >> 4, c4 = (i & 15) << 2;
        r[u] = *(const float4*)&g[rr * ldg + coff + c4];
    }
}
__device__ __forceinline__ void writeW32(const float4* r, float* Ws) {
#pragma unroll
    for (int u = 0; u < 2; u++) ((float4*)Ws)[threadIdx.x + u * 256] = r[u];
}

// acc[4][4] += A[tr*4+i][k] * W[k][tc*4+j], k in [0,32)
__device__ __forceinline__ void mac8v(const float (*As)[AST2], const float* __restrict__ Ws,
                                      float (*acc)[4], int tr, int tc) {
#pragma unroll
    for (int k4 = 0; k4 < 32; k4 += 4) {
        float4 a0 = *(const float4*)&As[tr * 4 + 0][k4];
        float4 a1 = *(const float4*)&As[tr * 4 + 1][k4];
        float4 a2 = *(const float4*)&As[tr * 4 + 2][k4];
        float4 a3 = *(const float4*)&As[tr * 4 + 3][k4];
#pragma unroll
        for (int j = 0; j < 4; j++) {
            float4 w = *(const float4*)&Ws[(k4 + j) * 64 + tc * 4];
            float e0 = (&a0.x)[j], e1 = (&a1.x)[j], e2 = (&a2.x)[j], e3 = (&a3.x)[j];
            acc[0][0] += e0 * w.x; acc[0][1] += e0 * w.y; acc[0][2] += e0 * w.z; acc[0][3] += e0 * w.w;
            acc[1][0] += e1 * w.x; acc[1][1] += e1 * w.y; acc[1][2] += e1 * w.z; acc[1][3] += e1 * w.w;
            acc[2][0] += e2 * w.x; acc[2][1] += e2 * w.y; acc[2][2] += e2 * w.z; acc[2][3] += e2 * w.w;
            acc[3][0] += e3 * w.x; acc[3][1] += e3 * w.y; acc[3][2] += e3 * w.z; acc[3][3] += e3 * w.w;
        }
    }
}

// dual-W over the same A chunk
__device__ __forceinline__ void mac8v2(const float (*As)[AST2], const float* __restrict__ W0,
                                       const float* __restrict__ W1, float (*accA)[4],
                                       float (*accB)[4], int tr, int tc) {
#pragma unroll
    for (int k4 = 0; k4 < 32; k4 += 4) {
        float4 a0 = *(const float4*)&As[tr * 4 + 0][k4];
        float4 a1 = *(const float4*)&As[tr * 4 + 1][k4];
        float4 a2 = *(const float4*)&As[tr * 4 + 2][k4];
        float4 a3 = *(const float4*)&As[tr * 4 + 3][k4];
#pragma unroll
        for (int j = 0; j < 4; j++) {
            float e0 = (&a0.x)[j], e1 = (&a1.x)[j], e2 = (&a2.x)[j], e3 = (&a3.x)[j];
            float4 w = *(const float4*)&W0[(k4 + j) * 64 + tc * 4];
            accA[0][0] += e0 * w.x; accA[0][1] += e0 * w.y; accA[0][2] += e0 * w.z; accA[0][3] += e0 * w.w;
            accA[1][0] += e1 * w.x; accA[1][1] += e1 * w.y; accA[1][2] += e1 * w.z; accA[1][3] += e1 * w.w;
            accA[2][0] += e2 * w.x; accA[2][1] += e2 * w.y; accA[2][2] += e2 * w.z; accA[2][3] += e2 * w.w;
            accA[3][0] += e3 * w.x; accA[3][1] += e3 * w.y; accA[3][2] += e3 * w.z; accA[3][3] += e3 * w.w;
            float4 u = *(const float4*)&W1[(k4 + j) * 64 + tc * 4];
            accB[0][0] += e0 * u.x; accB[0][1] += e0 * u.y; accB[0][2] += e0 * u.z; accB[0][3] += e0 * u.w;
            accB[1][0] += e1 * u.x; accB[1][1] += e1 * u.y; accB[1][2] += e1 * u.z; accB[1][3] += e1 * u.w;
            accB[2][0] += e2 * u.x; accB[2][1] += e2 * u.y; accB[2][2] += e2 * u.z; accB[2][3] += e2 * u.w;
            accB[3][0] += e3 * u.x; accB[3][1] += e3 * u.y; accB[3][2] += e3 * u.z; accB[3][3] += e3 * u.w;
        }
    }
}

// ================= n2v projection (prefetched) =================
__global__ __launch_bounds__(256, 4) void k_n2vp_t(const float* __restrict__ n2v,
                                                   const float* __restrict__ w,
                                                   const float* __restrict__ b,
                                                   float* __restrict__ n2vp) {
    __shared__ float As[64][AST2];
    __shared__ float W0[32 * 64];
    int nbase = blockIdx.x * 64;
    int tc = threadIdx.x & 15, tr = threadIdx.x >> 4;
    float acc[4][4] = {};
    float4 aR[2], wR[2];
    loadA32(n2v, nbase, EMBD, 0, aR);
    loadW32(w, wR);
    for (int c = 0; c < 4; c++) {
        writeA32(aR, As);
        writeW32(wR, W0);
        __syncthreads();
        if (c < 3) {
            loadA32(n2v, nbase, EMBD, (c + 1) * 32, aR);
            loadW32(w + (c + 1) * 2048, wR);
        }
        mac8v(As, W0, acc, tr, tc);
        __syncthreads();
    }
    float b0 = b[tc * 4], b1 = b[tc * 4 + 1], b2 = b[tc * 4 + 2], b3 = b[tc * 4 + 3];
#pragma unroll
    for (int i = 0; i < 4; i++) {
        int row = nbase + tr * 4 + i;
        if (row < NN) {
            float4 o = {acc[i][0] + b0, acc[i][1] + b1, acc[i][2] + b2, acc[i][3] + b3};
            *(float4*)&n2vp[(size_t)row * HD + tc * 4] = o;
        }
    }
}

// ================= front: h0 = raw + sigmoid(gate) * delta (prefetched) =================
__global__ __launch_bounds__(256, 4) void k_front_t(const float* __restrict__ x,
                                                    const float* __restrict__ n2vp,
                                                    const float* __restrict__ ip_w,
                                                    const float* __restrict__ ip_b,
                                                    const float* __restrict__ gate_w,
                                                    const float* __restrict__ gate_b,
                                                    float* __restrict__ h0) {
    __shared__ float As[64][AST2];
    __shared__ float W0[32 * 64];
    __shared__ float W1[32 * 64];
    int nbase = blockIdx.x * 64;
    int tc = threadIdx.x & 15, tr = threadIdx.x >> 4;
    float araw[4][4] = {}, ag[4][4] = {}, adel[4][4] = {};
    float4 aR[2], w0R[2], w1R[2];
    loadA32(x, nbase, DIN, 0, aR);
    loadW32(ip_w, w0R);
    loadW32(gate_w, w1R);
    // chunks 0..7: x ; chunks 8..9: n2vp
    for (int c = 0; c < 10; c++) {
        writeA32(aR, As);
        writeW32(w0R, W0);
        writeW32(w1R, W1);
        __syncthreads();
        int nxt = c + 1;
        if (nxt < 8) {
            loadA32(x, nbase, DIN, nxt * 32, aR);
            loadW32(ip_w + nxt * 2048, w0R);
            loadW32(gate_w + nxt * 2048, w1R);
        } else if (nxt < 10) {
            int cc = nxt - 8;
            loadA32(n2vp, nbase, HD, cc * 32, aR);
            loadW32(ip_w + (DIN + cc * 32) * 64, w0R);
            loadW32(gate_w + (DIN + cc * 32) * 64, w1R);
        }
        if (c < 8) mac8v2(As, W0, W1, araw, ag, tr, tc);
        else       mac8v2(As, W0, W1, adel, ag, tr, tc);
        __syncthreads();
    }
    float ib0 = ip_b[tc * 4], ib1 = ip_b[tc * 4 + 1], ib2 = ip_b[tc * 4 + 2], ib3 = ip_b[tc * 4 + 3];
    float gb0 = gate_b[tc * 4], gb1 = gate_b[tc * 4 + 1], gb2 = gate_b[tc * 4 + 2], gb3 = gate_b[tc * 4 + 3];
#pragma unroll
    for (int i = 0; i < 4; i++) {
        int row = nbase + tr * 4 + i;
        if (row < NN) {
            float r0 = araw[i][0] + ib0, r1 = araw[i][1] + ib1, r2 = araw[i][2] + ib2, r3 = araw[i][3] + ib3;
            float s0 = 1.f / (1.f + __expf(-(ag[i][0] + gb0)));
            float s1 = 1.f / (1.f + __expf(-(ag[i][1] + gb1)));
            float s2 = 1.f / (1.f + __expf(-(ag[i][2] + gb2)));
            float s3 = 1.f / (1.f + __expf(-(ag[i][3] + gb3)));
            float4 o = {r0 + s0 * adel[i][0], r1 + s1 * adel[i][1],
                        r2 + s2 * adel[i][2], r3 + s3 * adel[i][3]};
            *(float4*)&h0[(size_t)row * HD + tc * 4] = o;
        }
    }
}

// ================= gather mean =================
__global__ void k_gather_mean(const int* __restrict__ rowptr, const int* __restrict__ colsrc,
                              const float* __restrict__ invdeg, const float* __restrict__ hin,
                              float* __restrict__ agg) {
    int t = threadIdx.x & 63;
    int gw = blockIdx.x * (blockDim.x >> 6) + (threadIdx.x >> 6);
    int stride = gridDim.x * (blockDim.x >> 6);
    for (int n = gw; n < NN; n += stride) {
        int bg = rowptr[n], en = rowptr[n + 1];
        float acc = 0.f;
        int i = bg;
        for (; i + 4 <= en; i += 4) {
            int s0 = colsrc[i], s1 = colsrc[i + 1], s2 = colsrc[i + 2], s3 = colsrc[i + 3];
            acc += hin[(size_t)s0 * HD + t] + hin[(size_t)s1 * HD + t] +
                   hin[(size_t)s2 * HD + t] + hin[(size_t)s3 * HD + t];
        }
        for (; i < en; i++) acc += hin[(size_t)colsrc[i] * HD + t];
        agg[(size_t)n * HD + t] = acc * invdeg[n];
    }
}

// ================= SAGE combine (prefetched, 4 phases) =================
__global__ __launch_bounds__(256, 4) void k_sage_t(const float* __restrict__ agg,
                                                   const float* __restrict__ h,
                                                   const float* __restrict__ wl,
                                                   const float* __restrict__ bl,
                                                   const float* __restrict__ wr,
                                                   float* __restrict__ hout) {
    __shared__ float As[64][AST2];
    __shared__ float W0[32 * 64];
    int nbase = blockIdx.x * 64;
    int tc = threadIdx.x & 15, tr = threadIdx.x >> 4;
    float acc[4][4] = {};
    float4 aR[2], wR[2];
    loadA32(agg, nbase, HD, 0, aR);
    loadW32(wl, wR);
    // phase 0: agg k0/wl0 ; 1: agg k32/wl1 ; 2: h k0/wr0 ; 3: h k32/wr1
    for (int c = 0; c < 4; c++) {
        writeA32(aR, As);
        writeW32(wR, W0);
        __syncthreads();
        if (c == 0) { loadA32(agg, nbase, HD, 32, aR); loadW32(wl + 2048, wR); }
        else if (c == 1) { loadA32(h, nbase, HD, 0, aR); loadW32(wr, wR); }
        else if (c == 2) { loadA32(h, nbase, HD, 32, aR); loadW32(wr + 2048, wR); }
        mac8v(As, W0, acc, tr, tc);
        __syncthreads();
    }
    float b0 = bl[tc * 4], b1 = bl[tc * 4 + 1], b2 = bl[tc * 4 + 2], b3 = bl[tc * 4 + 3];
#pragma unroll
    for (int i = 0; i < 4; i++) {
        int row = nbase + tr * 4 + i;
        if (row < NN) {
            float4 o = {fmaxf(acc[i][0] + b0, 0.f), fmaxf(acc[i][1] + b1, 0.f),
                        fmaxf(acc[i][2] + b2, 0.f), fmaxf(acc[i][3] + b3, 0.f)};
            *(float4*)&hout[(size_t)row * HD + tc * 4] = o;
        }
    }
}

// ================= GAT transform (prefetched, dual-W) =================
__global__ __launch_bounds__(256, 4) void k_gatxh_t(const float* __restrict__ h,
                                                    const float* __restrict__ w,
                                                    const float* __restrict__ att_s,
                                                    const float* __restrict__ att_d,
                                                    float* __restrict__ xh,
                                                    float* __restrict__ a_s,
                                                    float* __restrict__ a_d) {
    __shared__ float As[64][AST2];
    __shared__ float W0[32 * 64];
    __shared__ float W1[32 * 64];
    int nbase = blockIdx.x * 64;
    int tc = threadIdx.x & 15, tr = threadIdx.x >> 4;
    float acc0[4][4] = {}, acc1[4][4] = {};
    float4 aR[2], w0R[2], w1R[2];
    loadA32(h, nbase, HD, 0, aR);
    loadW32cols(w, 128, 0, w0R);
    loadW32cols(w, 128, 64, w1R);
    for (int c = 0; c < 2; c++) {
        writeA32(aR, As);
        writeW32(w0R, W0);
        writeW32(w1R, W1);
        __syncthreads();
        if (c == 0) {
            loadA32(h, nbase, HD, 32, aR);
            loadW32cols(w + 32 * 128, 128, 0, w0R);
            loadW32cols(w + 32 * 128, 128, 64, w1R);
        }
        mac8v2(As, W0, W1, acc0, acc1, tr, tc);
        __syncthreads();
    }
#pragma unroll
    for (int half = 0; half < 2; half++) {
        float(*acc)[4] = half ? acc1 : acc0;
        float as0 = att_s[half * 64 + tc * 4], as1 = att_s[half * 64 + tc * 4 + 1];
        float as2 = att_s[half * 64 + tc * 4 + 2], as3 = att_s[half * 64 + tc * 4 + 3];
        float ad0 = att_d[half * 64 + tc * 4], ad1 = att_d[half * 64 + tc * 4 + 1];
        float ad2 = att_d[half * 64 + tc * 4 + 2], ad3 = att_d[half * 64 + tc * 4 + 3];
#pragma unroll
        for (int i = 0; i < 4; i++) {
            int row = nbase + tr * 4 + i;
            float ps = acc[i][0] * as0 + acc[i][1] * as1 + acc[i][2] * as2 + acc[i][3] * as3;
            float pd = acc[i][0] * ad0 + acc[i][1] * ad1 + acc[i][2] * ad2 + acc[i][3] * ad3;
#pragma unroll
            for (int off = 8; off; off >>= 1) {
                ps += __shfl_xor(ps, off);
                pd += __shfl_xor(pd, off);
            }
            if (row < NN) {
                *(float4*)&xh[(size_t)row * 128 + half * 64 + tc * 4] = *(float4*)&acc[i][0];
                if (tc == 0) {
                    a_s[row * 2 + half] = ps;
                    a_d[row * 2 + half] = pd;
                }
            }
        }
    }
}

// ================= GAT fused: single pass (no max-subtraction; math-identical) =================
__global__ void k_gat_fused(const int* __restrict__ rowptr, const int* __restrict__ colsrc,
                            const float* __restrict__ a_s, const float* __restrict__ a_d,
                            const float* __restrict__ xh, const float* __restrict__ gb,
                            float* __restrict__ hout) {
    int t = threadIdx.x & 63;
    float bias = gb[t];
    int gw = blockIdx.x * (blockDim.x >> 6) + (threadIdx.x >> 6);
    int stride = gridDim.x * (blockDim.x >> 6);
    for (int n = gw; n < NN; n += stride) {
        int bg = rowptr[n], en = rowptr[n + 1];
        float ad0 = a_d[n * 2], ad1 = a_d[n * 2 + 1];
        float ws0 = __expf(lrelu(a_s[n * 2] + ad0));
        float ws1 = __expf(lrelu(a_s[n * 2 + 1] + ad1));
        float s0 = ws0, s1 = ws1;
        float acc0 = ws0 * xh[(size_t)n * 128 + t];
        float acc1 = ws1 * xh[(size_t)n * 128 + 64 + t];
        int i = bg;
        for (; i + 2 <= en; i += 2) {
            int sa = colsrc[i], sb = colsrc[i + 1];
            float wa0 = __expf(lrelu(a_s[sa * 2] + ad0));
            float wa1 = __expf(lrelu(a_s[sa * 2 + 1] + ad1));
            float wb0 = __expf(lrelu(a_s[sb * 2] + ad0));
            float wb1 = __expf(lrelu(a_s[sb * 2 + 1] + ad1));
            float xa0 = xh[(size_t)sa * 128 + t], xa1 = xh[(size_t)sa * 128 + 64 + t];
            float xb0 = xh[(size_t)sb * 128 + t], xb1 = xh[(size_t)sb * 128 + 64 + t];
            s0 += wa0 + wb0;
            s1 += wa1 + wb1;
            acc0 += wa0 * xa0 + wb0 * xb0;
            acc1 += wa1 * xa1 + wb1 * xb1;
        }
        for (; i < en; i++) {
            int s = colsrc[i];
            float w0 = __expf(lrelu(a_s[s * 2] + ad0));
            float w1 = __expf(lrelu(a_s[s * 2 + 1] + ad1));
            s0 += w0;
            s1 += w1;
            acc0 += w0 * xh[(size_t)s * 128 + t];
            acc1 += w1 * xh[(size_t)s * 128 + 64 + t];
        }
        float r0 = 0.5f / (s0 + 1e-16f), r1 = 0.5f / (s1 + 1e-16f);
        hout[(size_t)n * HD + t] = fmaxf(acc0 * r0 + acc1 * r1 + bias, 0.f);
    }
}

// ================= final SAGE =================
__global__ void k_pfin(const float* __restrict__ h, const float* __restrict__ wl,
                       float* __restrict__ P) {
    __shared__ float sw[HD * OUTD];
    for (int i = threadIdx.x; i < HD * OUTD; i += blockDim.x) sw[i] = wl[i];
    __syncthreads();
    int t = threadIdx.x & 63;
    int c = t & 31, half = t >> 5;
    int gw = blockIdx.x * (blockDim.x >> 6) + (threadIdx.x >> 6);
    int stride = gridDim.x * (blockDim.x >> 6);
    for (int n = gw; n < NN; n += stride) {
        float hv = h[(size_t)n * HD + t];
        float acc = 0.f;
#pragma unroll 8
        for (int i = 0; i < 32; i++) {
            float bb = __shfl(hv, half * 32 + i);
            acc += bb * sw[half * 1024 + i * 32 + c];
        }
        acc += __shfl_xor(acc, 32);
        if (half == 0) P[(size_t)n * OUTD + c] = acc;
    }
}

__global__ void k_final_fused(const int* __restrict__ rowptr, const int* __restrict__ colsrc,
                              const float* __restrict__ invdeg, const float* __restrict__ P,
                              const float* __restrict__ h, const float* __restrict__ bl,
                              const float* __restrict__ wr, float* __restrict__ out) {
    __shared__ float sw[HD * OUTD];
    for (int i = threadIdx.x; i < HD * OUTD; i += blockDim.x) sw[i] = wr[i];
    __syncthreads();
    int t = threadIdx.x & 63;
    int j = t & 31, half = t >> 5;
    float bias = bl[j];
    int gw = blockIdx.x * (blockDim.x >> 6) + (threadIdx.x >> 6);
    int stride = gridDim.x * (blockDim.x >> 6);
    for (int n = gw; n < NN; n += stride) {
        int bg = rowptr[n], en = rowptr[n + 1];
        float acc = 0.f;
        for (int i = bg + half; i < en; i += 2) acc += P[(size_t)colsrc[i] * OUTD + j];
        acc += __shfl_xor(acc, 32);
        float hv = h[(size_t)n * HD + t];
        float o = 0.f;
#pragma unroll 8
        for (int i2 = 0; i2 < 32; i2++) {
            float bb = __shfl(hv, half * 32 + i2);
            o += bb * sw[half * 1024 + i2 * 32 + j];
        }
        o += __shfl_xor(o, 32);
        if (half == 0) out[(size_t)n * OUTD + j] = acc * invdeg[n] + bias + o;
    }
}

// ================= launch =================
extern "C" void kernel_launch(void* const* d_in, const int* in_sizes, int n_in,
                              void* d_out, int out_size, void* d_ws, size_t ws_size,
                              hipStream_t stream) {
    const float* x      = (const float*)d_in[0];
    const int*   eidx   = (const int*)d_in[1];
    const float* n2v    = (const float*)d_in[2];
    const float* n2v_w  = (const float*)d_in[3];
    const float* n2v_b  = (const float*)d_in[4];
    const float* ip_w   = (const float*)d_in[5];
    const float* ip_b   = (const float*)d_in[6];
    const float* gate_w = (const float*)d_in[7];
    const float* gate_b = (const float*)d_in[8];
    const float* s0_wl  = (const float*)d_in[9];
    const float* s0_bl  = (const float*)d_in[10];
    const float* s0_wr  = (const float*)d_in[11];
    const float* s1_wl  = (const float*)d_in[12];
    const float* s1_bl  = (const float*)d_in[13];
    const float* s1_wr  = (const float*)d_in[14];
    const float* gat_w  = (const float*)d_in[15];
    const float* att_s  = (const float*)d_in[16];
    const float* att_d  = (const float*)d_in[17];
    const float* gat_b  = (const float*)d_in[18];
    const float* f_wl   = (const float*)d_in[19];
    const float* f_bl   = (const float*)d_in[20];
    const float* f_wr   = (const float*)d_in[21];

    const int* src = eidx;
    const int* dst = eidx + NE;

    // ---- workspace ----
    float* ws     = (float*)d_ws;
    float* invdeg = ws;                        // N
    float* S1     = invdeg + NN;               // 64N
    float* S2     = S1 + (size_t)NN * HD;      // 64N
    float* S4     = S2 + (size_t)NN * HD;      // 128N: [agg | n2vp] then xh
    float* a_s    = S4 + (size_t)NN * 128;     // 2N
    float* a_d    = a_s + (size_t)NN * 2;      // 2N
    float* P      = a_d + (size_t)NN * 2;      // 32N
    int*   cnt    = (int*)(P + (size_t)NN * OUTD);
    int*   rowptr = cnt + NN;
    int*   cursor = rowptr + NN + 1;
    int*   blksum = cursor + NN;               // 128
    int*   colsrc = blksum + 128;              // NE

    float* agg  = S4;
    float* n2vp = S4 + (size_t)NN * HD;
    float* xh   = S4;
    float* out  = (float*)d_out;

    const int BT = 256;
    dim3 b128(128), b256(BT);
    int eblk = (NE + BT - 1) / BT;
    int nblk = (NN + BT - 1) / BT;

    // ---- CSR ----
    hipMemsetAsync(cnt, 0, (size_t)NN * 4, stream);
    k_count<<<eblk, b256, 0, stream>>>(dst, cnt);
    k_scan1<<<SNBLK, b256, 0, stream>>>(cnt, rowptr, blksum);
    k_scan2<<<1, b128, 0, stream>>>(blksum);
    k_scan3<<<nblk, b256, 0, stream>>>(blksum, cnt, rowptr, cursor, invdeg);
    k_fill<<<eblk, b256, 0, stream>>>(src, dst, cursor, colsrc);

    // ---- front ----
    k_n2vp_t<<<NT, b256, 0, stream>>>(n2v, n2v_w, n2v_b, n2vp);
    k_front_t<<<NT, b256, 0, stream>>>(x, n2vp, ip_w, ip_b, gate_w, gate_b, S2);

    // ---- SAGE 0: S2 -> S1 ----
    k_gather_mean<<<2048, b256, 0, stream>>>(rowptr, colsrc, invdeg, S2, agg);
    k_sage_t<<<NT, b256, 0, stream>>>(agg, S2, s0_wl, s0_bl, s0_wr, S1);

    // ---- SAGE 1: S1 -> S2 ----
    k_gather_mean<<<2048, b256, 0, stream>>>(rowptr, colsrc, invdeg, S1, agg);
    k_sage_t<<<NT, b256, 0, stream>>>(agg, S1, s1_wl, s1_bl, s1_wr, S2);

    // ---- GAT: S2 -> S1 ----
    k_gatxh_t<<<NT, b256, 0, stream>>>(S2, gat_w, att_s, att_d, xh, a_s, a_d);
    k_gat_fused<<<2048, b256, 0, stream>>>(rowptr, colsrc, a_s, a_d, xh, gat_b, S1);

    // ---- final SAGE: S1 -> out ----
    k_pfin<<<2048, b256, 0, stream>>>(S1, f_wl, P);
    k_final_fused<<<2048, b256, 0, stream>>>(rowptr, colsrc, invdeg, P, S1, f_bl, f_wr, out);
}

// Round 10
// 845.107 us; speedup vs baseline: 1.2619x; 1.2619x over previous
//
#include <hip/hip_runtime.h>
#include <math.h>

#define NN 100000
#define NE 1600000
#define DIN 256
#define HD 64
#define OUTD 32
#define EMBD 128
#define SLOPE 0.2f
#define AST 65
#define NT ((NN + 63) / 64)
#define SCHUNK 1024
#define SNBLK ((NN + SCHUNK - 1) / SCHUNK)   // 98

__device__ __forceinline__ float lrelu(float x) { return x > 0.f ? x : SLOPE * x; }
__device__ __forceinline__ ushort f2b(float f) {
    unsigned u = __float_as_uint(f);
    return (ushort)((u + 0x7FFFu + ((u >> 16) & 1u)) >> 16);  // RTNE fp32->bf16
}
__device__ __forceinline__ float b2f(ushort v) { return __uint_as_float(((unsigned)v) << 16); }

// ================= CSR build =================
__global__ void k_count(const int* __restrict__ dst, int* __restrict__ cnt) {
    int i = blockIdx.x * blockDim.x + threadIdx.x;
    if (i < NE) atomicAdd(&cnt[dst[i]], 1);
}

__global__ __launch_bounds__(256) void k_scan1(const int* __restrict__ cnt,
                                               int* __restrict__ rowptr,
                                               int* __restrict__ blksum) {
    __shared__ int ts[256];
    int base = blockIdx.x * SCHUNK + threadIdx.x * 4;
    int v0 = 0, v1 = 0, v2 = 0, v3 = 0;
    if (base < NN)     v0 = cnt[base];
    if (base + 1 < NN) v1 = cnt[base + 1];
    if (base + 2 < NN) v2 = cnt[base + 2];
    if (base + 3 < NN) v3 = cnt[base + 3];
    int s = v0 + v1 + v2 + v3;
    ts[threadIdx.x] = s;
    __syncthreads();
    for (int off = 1; off < 256; off <<= 1) {
        int w = (threadIdx.x >= off) ? ts[threadIdx.x - off] : 0;
        __syncthreads();
        ts[threadIdx.x] += w;
        __syncthreads();
    }
    int excl = ts[threadIdx.x] - s;
    if (base < NN)     rowptr[base]     = excl;
    if (base + 1 < NN) rowptr[base + 1] = excl + v0;
    if (base + 2 < NN) rowptr[base + 2] = excl + v0 + v1;
    if (base + 3 < NN) rowptr[base + 3] = excl + v0 + v1 + v2;
    if (threadIdx.x == 255) blksum[blockIdx.x] = ts[255];
}

__global__ __launch_bounds__(128) void k_scan2(int* __restrict__ blksum) {
    __shared__ int ts[128];
    int t = threadIdx.x;
    int v = (t < SNBLK) ? blksum[t] : 0;
    ts[t] = v;
    __syncthreads();
    for (int off = 1; off < 128; off <<= 1) {
        int w = (t >= off) ? ts[t - off] : 0;
        __syncthreads();
        ts[t] += w;
        __syncthreads();
    }
    if (t < SNBLK) blksum[t] = ts[t] - v;
}

__global__ void k_scan3(const int* __restrict__ blksum, const int* __restrict__ cnt,
                        int* __restrict__ rowptr, int* __restrict__ cursor,
                        float* __restrict__ invdeg) {
    int i = blockIdx.x * blockDim.x + threadIdx.x;
    if (i < NN) {
        int v = rowptr[i] + blksum[i >> 10];
        rowptr[i] = v;
        cursor[i] = v;
        invdeg[i] = 1.0f / fmaxf((float)cnt[i], 1.0f);
    }
    if (i == 0) rowptr[NN] = NE;
}

__global__ void k_fill(const int* __restrict__ src, const int* __restrict__ dst,
                       int* __restrict__ cursor, int* __restrict__ colsrc) {
    int i = blockIdx.x * blockDim.x + threadIdx.x;
    if (i >= NE) return;
    int pos = atomicAdd(&cursor[dst[i]], 1);
    colsrc[pos] = src[i];
}

// ================= tiled GEMM helpers (R5 baseline: K=64, scalar-A mac) =================
__device__ __forceinline__ void stageA(const float* __restrict__ g, int nbase, int ldg, int koff,
                                       float (*As)[AST]) {
    for (int i = threadIdx.x; i < 1024; i += 256) {
        int m = i >> 4, k4 = (i & 15) << 2;
        int row = nbase + m;
        if (row >= NN) row = NN - 1;
        float4 v = *(const float4*)&g[(size_t)row * ldg + koff + k4];
        As[m][k4] = v.x; As[m][k4 + 1] = v.y; As[m][k4 + 2] = v.z; As[m][k4 + 3] = v.w;
    }
}
__device__ __forceinline__ void stageW(const float* __restrict__ g, float* Ws) {
    for (int i = threadIdx.x; i < 1024; i += 256) ((float4*)Ws)[i] = ((const float4*)g)[i];
}
__device__ __forceinline__ void stageWcols(const float* __restrict__ g, int ldg, int coff,
                                           float* Ws) {
    for (int i = threadIdx.x; i < 1024; i += 256) {
        int r = i >> 4, c4 = (i & 15) << 2;
        *(float4*)&Ws[r * 64 + c4] = *(const float4*)&g[r * ldg + coff + c4];
    }
}
__device__ __forceinline__ void mac16(const float (*As)[AST], const float* __restrict__ Ws,
                                      float (*acc)[4], int tr, int tc) {
    const float* a0p = As[tr * 4 + 0];
    const float* a1p = As[tr * 4 + 1];
    const float* a2p = As[tr * 4 + 2];
    const float* a3p = As[tr * 4 + 3];
#pragma unroll 8
    for (int k = 0; k < 64; k++) {
        float4 w = *(const float4*)&Ws[k * 64 + tc * 4];
        float a0 = a0p[k], a1 = a1p[k], a2 = a2p[k], a3 = a3p[k];
        acc[0][0] += a0 * w.x; acc[0][1] += a0 * w.y; acc[0][2] += a0 * w.z; acc[0][3] += a0 * w.w;
        acc[1][0] += a1 * w.x; acc[1][1] += a1 * w.y; acc[1][2] += a1 * w.z; acc[1][3] += a1 * w.w;
        acc[2][0] += a2 * w.x; acc[2][1] += a2 * w.y; acc[2][2] += a2 * w.z; acc[2][3] += a2 * w.w;
        acc[3][0] += a3 * w.x; acc[3][1] += a3 * w.y; acc[3][2] += a3 * w.z; acc[3][3] += a3 * w.w;
    }
}

// ================= front =================
__global__ __launch_bounds__(256) void k_n2vp_t(const float* __restrict__ n2v,
                                                const float* __restrict__ w,
                                                const float* __restrict__ b,
                                                float* __restrict__ n2vp) {
    __shared__ float As[64][AST];
    __shared__ float Ws[64 * 64];
    int nbase = blockIdx.x * 64;
    int tc = threadIdx.x & 15, tr = threadIdx.x >> 4;
    float acc[4][4] = {};
    for (int c = 0; c < 2; c++) {
        if (c) __syncthreads();
        stageA(n2v, nbase, EMBD, c * 64, As);
        stageW(w + c * 64 * 64, Ws);
        __syncthreads();
        mac16(As, Ws, acc, tr, tc);
    }
    float b0 = b[tc * 4], b1 = b[tc * 4 + 1], b2 = b[tc * 4 + 2], b3 = b[tc * 4 + 3];
#pragma unroll
    for (int i = 0; i < 4; i++) {
        int row = nbase + tr * 4 + i;
        if (row < NN) {
            float4 o = {acc[i][0] + b0, acc[i][1] + b1, acc[i][2] + b2, acc[i][3] + b3};
            *(float4*)&n2vp[(size_t)row * HD + tc * 4] = o;
        }
    }
}

__global__ __launch_bounds__(256) void k_front_t(const float* __restrict__ x,
                                                 const float* __restrict__ n2vp,
                                                 const float* __restrict__ ip_w,
                                                 const float* __restrict__ ip_b,
                                                 const float* __restrict__ gate_w,
                                                 const float* __restrict__ gate_b,
                                                 float* __restrict__ h0,
                                                 ushort* __restrict__ h0b) {
    __shared__ float As[64][AST];
    __shared__ float Ws[64 * 64];
    int nbase = blockIdx.x * 64;
    int tc = threadIdx.x & 15, tr = threadIdx.x >> 4;
    float araw[4][4] = {}, ag[4][4] = {}, adel[4][4] = {};
    for (int c = 0; c < 4; c++) {
        if (c) __syncthreads();
        stageA(x, nbase, DIN, c * 64, As);
        stageW(ip_w + c * 64 * 64, Ws);
        __syncthreads();
        mac16(As, Ws, araw, tr, tc);
        __syncthreads();
        stageW(gate_w + c * 64 * 64, Ws);
        __syncthreads();
        mac16(As, Ws, ag, tr, tc);
    }
    __syncthreads();
    stageA(n2vp, nbase, HD, 0, As);
    stageW(ip_w + DIN * 64, Ws);
    __syncthreads();
    mac16(As, Ws, adel, tr, tc);
    __syncthreads();
    stageW(gate_w + DIN * 64, Ws);
    __syncthreads();
    mac16(As, Ws, ag, tr, tc);

    float ib0 = ip_b[tc * 4], ib1 = ip_b[tc * 4 + 1], ib2 = ip_b[tc * 4 + 2], ib3 = ip_b[tc * 4 + 3];
    float gb0 = gate_b[tc * 4], gb1 = gate_b[tc * 4 + 1], gb2 = gate_b[tc * 4 + 2], gb3 = gate_b[tc * 4 + 3];
#pragma unroll
    for (int i = 0; i < 4; i++) {
        int row = nbase + tr * 4 + i;
        if (row < NN) {
            float r0 = araw[i][0] + ib0, r1 = araw[i][1] + ib1, r2 = araw[i][2] + ib2, r3 = araw[i][3] + ib3;
            float s0 = 1.f / (1.f + __expf(-(ag[i][0] + gb0)));
            float s1 = 1.f / (1.f + __expf(-(ag[i][1] + gb1)));
            float s2 = 1.f / (1.f + __expf(-(ag[i][2] + gb2)));
            float s3 = 1.f / (1.f + __expf(-(ag[i][3] + gb3)));
            float4 o = {r0 + s0 * adel[i][0], r1 + s1 * adel[i][1],
                        r2 + s2 * adel[i][2], r3 + s3 * adel[i][3]};
            *(float4*)&h0[(size_t)row * HD + tc * 4] = o;
            ushort4 ob = {f2b(o.x), f2b(o.y), f2b(o.z), f2b(o.w)};
            *(ushort4*)&h0b[(size_t)row * HD + tc * 4] = ob;
        }
    }
}

// ================= gather mean (bf16 source) =================
__global__ void k_gather_mean(const int* __restrict__ rowptr, const int* __restrict__ colsrc,
                              const float* __restrict__ invdeg, const ushort* __restrict__ hb,
                              float* __restrict__ agg) {
    int t = threadIdx.x & 63;
    int gw = blockIdx.x * (blockDim.x >> 6) + (threadIdx.x >> 6);
    int stride = gridDim.x * (blockDim.x >> 6);
    for (int n = gw; n < NN; n += stride) {
        int bg = rowptr[n], en = rowptr[n + 1];
        float acc = 0.f;
        int i = bg;
        for (; i + 4 <= en; i += 4) {
            int s0 = colsrc[i], s1 = colsrc[i + 1], s2 = colsrc[i + 2], s3 = colsrc[i + 3];
            acc += b2f(hb[(size_t)s0 * HD + t]) + b2f(hb[(size_t)s1 * HD + t]) +
                   b2f(hb[(size_t)s2 * HD + t]) + b2f(hb[(size_t)s3 * HD + t]);
        }
        for (; i < en; i++) acc += b2f(hb[(size_t)colsrc[i] * HD + t]);
        agg[(size_t)n * HD + t] = acc * invdeg[n];
    }
}

// ================= SAGE combine (fp32 dense; emits fp32 + bf16 copy) =================
__global__ __launch_bounds__(256) void k_sage_t(const float* __restrict__ agg,
                                                const float* __restrict__ h,
                                                const float* __restrict__ wl,
                                                const float* __restrict__ bl,
                                                const float* __restrict__ wr,
                                                float* __restrict__ hout,
                                                ushort* __restrict__ houtb) {
    __shared__ float As[64][AST];
    __shared__ float Ws[64 * 64];
    int nbase = blockIdx.x * 64;
    int tc = threadIdx.x & 15, tr = threadIdx.x >> 4;
    float acc[4][4] = {};
    stageA(agg, nbase, HD, 0, As);
    stageW(wl, Ws);
    __syncthreads();
    mac16(As, Ws, acc, tr, tc);
    __syncthreads();
    stageA(h, nbase, HD, 0, As);
    stageW(wr, Ws);
    __syncthreads();
    mac16(As, Ws, acc, tr, tc);
    float b0 = bl[tc * 4], b1 = bl[tc * 4 + 1], b2 = bl[tc * 4 + 2], b3 = bl[tc * 4 + 3];
#pragma unroll
    for (int i = 0; i < 4; i++) {
        int row = nbase + tr * 4 + i;
        if (row < NN) {
            float4 o = {fmaxf(acc[i][0] + b0, 0.f), fmaxf(acc[i][1] + b1, 0.f),
                        fmaxf(acc[i][2] + b2, 0.f), fmaxf(acc[i][3] + b3, 0.f)};
            *(float4*)&hout[(size_t)row * HD + tc * 4] = o;
            ushort4 ob = {f2b(o.x), f2b(o.y), f2b(o.z), f2b(o.w)};
            *(ushort4*)&houtb[(size_t)row * HD + tc * 4] = ob;
        }
    }
}

// ================= GAT transform (xh emitted as bf16 only) =================
__global__ __launch_bounds__(256) void k_gatxh_t(const float* __restrict__ h,
                                                 const float* __restrict__ w,
                                                 const float* __restrict__ att_s,
                                                 const float* __restrict__ att_d,
                                                 ushort* __restrict__ xhb,
                                                 float* __restrict__ a_s,
                                                 float* __restrict__ a_d) {
    __shared__ float As[64][AST];
    __shared__ float Ws[64 * 64];
    int nbase = blockIdx.x * 64;
    int tc = threadIdx.x & 15, tr = threadIdx.x >> 4;
    stageA(h, nbase, HD, 0, As);
#pragma unroll
    for (int half = 0; half < 2; half++) {
        if (half) __syncthreads();
        stageWcols(w, 128, half * 64, Ws);
        __syncthreads();
        float acc[4][4] = {};
        mac16(As, Ws, acc, tr, tc);
        float as0 = att_s[half * 64 + tc * 4], as1 = att_s[half * 64 + tc * 4 + 1];
        float as2 = att_s[half * 64 + tc * 4 + 2], as3 = att_s[half * 64 + tc * 4 + 3];
        float ad0 = att_d[half * 64 + tc * 4], ad1 = att_d[half * 64 + tc * 4 + 1];
        float ad2 = att_d[half * 64 + tc * 4 + 2], ad3 = att_d[half * 64 + tc * 4 + 3];
#pragma unroll
        for (int i = 0; i < 4; i++) {
            int row = nbase + tr * 4 + i;
            float ps = acc[i][0] * as0 + acc[i][1] * as1 + acc[i][2] * as2 + acc[i][3] * as3;
            float pd = acc[i][0] * ad0 + acc[i][1] * ad1 + acc[i][2] * ad2 + acc[i][3] * ad3;
#pragma unroll
            for (int off = 8; off; off >>= 1) {
                ps += __shfl_xor(ps, off);
                pd += __shfl_xor(pd, off);
            }
            if (row < NN) {
                ushort4 ob = {f2b(acc[i][0]), f2b(acc[i][1]), f2b(acc[i][2]), f2b(acc[i][3])};
                *(ushort4*)&xhb[(size_t)row * 128 + half * 64 + tc * 4] = ob;
                if (tc == 0) {
                    a_s[row * 2 + half] = ps;
                    a_d[row * 2 + half] = pd;
                }
            }
        }
    }
}

// ================= GAT fused: single pass, bf16 xh gather =================
__global__ void k_gat_fused(const int* __restrict__ rowptr, const int* __restrict__ colsrc,
                            const float* __restrict__ a_s, const float* __restrict__ a_d,
                            const ushort* __restrict__ xhb, const float* __restrict__ gb,
                            float* __restrict__ hout) {
    int t = threadIdx.x & 63;
    float bias = gb[t];
    int gw = blockIdx.x * (blockDim.x >> 6) + (threadIdx.x >> 6);
    int stride = gridDim.x * (blockDim.x >> 6);
    for (int n = gw; n < NN; n += stride) {
        int bg = rowptr[n], en = rowptr[n + 1];
        float ad0 = a_d[n * 2], ad1 = a_d[n * 2 + 1];
        float ws0 = __expf(lrelu(a_s[n * 2] + ad0));
        float ws1 = __expf(lrelu(a_s[n * 2 + 1] + ad1));
        float s0 = ws0, s1 = ws1;
        float acc0 = ws0 * b2f(xhb[(size_t)n * 128 + t]);
        float acc1 = ws1 * b2f(xhb[(size_t)n * 128 + 64 + t]);
        int i = bg;
        for (; i + 2 <= en; i += 2) {
            int sa = colsrc[i], sb = colsrc[i + 1];
            float wa0 = __expf(lrelu(a_s[sa * 2] + ad0));
            float wa1 = __expf(lrelu(a_s[sa * 2 + 1] + ad1));
            float wb0 = __expf(lrelu(a_s[sb * 2] + ad0));
            float wb1 = __expf(lrelu(a_s[sb * 2 + 1] + ad1));
            float xa0 = b2f(xhb[(size_t)sa * 128 + t]), xa1 = b2f(xhb[(size_t)sa * 128 + 64 + t]);
            float xb0 = b2f(xhb[(size_t)sb * 128 + t]), xb1 = b2f(xhb[(size_t)sb * 128 + 64 + t]);
            s0 += wa0 + wb0;
            s1 += wa1 + wb1;
            acc0 += wa0 * xa0 + wb0 * xb0;
            acc1 += wa1 * xa1 + wb1 * xb1;
        }
        for (; i < en; i++) {
            int s = colsrc[i];
            float w0 = __expf(lrelu(a_s[s * 2] + ad0));
            float w1 = __expf(lrelu(a_s[s * 2 + 1] + ad1));
            s0 += w0;
            s1 += w1;
            acc0 += w0 * b2f(xhb[(size_t)s * 128 + t]);
            acc1 += w1 * b2f(xhb[(size_t)s * 128 + 64 + t]);
        }
        float r0 = 0.5f / (s0 + 1e-16f), r1 = 0.5f / (s1 + 1e-16f);
        hout[(size_t)n * HD + t] = fmaxf(acc0 * r0 + acc1 * r1 + bias, 0.f);
    }
}

// ================= final SAGE (fp32 P) =================
__global__ void k_pfin(const float* __restrict__ h, const float* __restrict__ wl,
                       float* __restrict__ P) {
    __shared__ float sw[HD * OUTD];
    for (int i = threadIdx.x; i < HD * OUTD; i += blockDim.x) sw[i] = wl[i];
    __syncthreads();
    int t = threadIdx.x & 63;
    int c = t & 31, half = t >> 5;
    int gw = blockIdx.x * (blockDim.x >> 6) + (threadIdx.x >> 6);
    int stride = gridDim.x * (blockDim.x >> 6);
    for (int n = gw; n < NN; n += stride) {
        float hv = h[(size_t)n * HD + t];
        float acc = 0.f;
#pragma unroll 8
        for (int i = 0; i < 32; i++) {
            float bb = __shfl(hv, half * 32 + i);
            acc += bb * sw[half * 1024 + i * 32 + c];
        }
        acc += __shfl_xor(acc, 32);
        if (half == 0) P[(size_t)n * OUTD + c] = acc;
    }
}

__global__ void k_final_fused(const int* __restrict__ rowptr, const int* __restrict__ colsrc,
                              const float* __restrict__ invdeg, const float* __restrict__ P,
                              const float* __restrict__ h, const float* __restrict__ bl,
                              const float* __restrict__ wr, float* __restrict__ out) {
    __shared__ float sw[HD * OUTD];
    for (int i = threadIdx.x; i < HD * OUTD; i += blockDim.x) sw[i] = wr[i];
    __syncthreads();
    int t = threadIdx.x & 63;
    int j = t & 31, half = t >> 5;
    float bias = bl[j];
    int gw = blockIdx.x * (blockDim.x >> 6) + (threadIdx.x >> 6);
    int stride = gridDim.x * (blockDim.x >> 6);
    for (int n = gw; n < NN; n += stride) {
        int bg = rowptr[n], en = rowptr[n + 1];
        float acc = 0.f;
        for (int i = bg + half; i < en; i += 2) acc += P[(size_t)colsrc[i] * OUTD + j];
        acc += __shfl_xor(acc, 32);
        float hv = h[(size_t)n * HD + t];
        float o = 0.f;
#pragma unroll 8
        for (int i2 = 0; i2 < 32; i2++) {
            float bb = __shfl(hv, half * 32 + i2);
            o += bb * sw[half * 1024 + i2 * 32 + j];
        }
        o += __shfl_xor(o, 32);
        if (half == 0) out[(size_t)n * OUTD + j] = acc * invdeg[n] + bias + o;
    }
}

// ================= launch =================
extern "C" void kernel_launch(void* const* d_in, const int* in_sizes, int n_in,
                              void* d_out, int out_size, void* d_ws, size_t ws_size,
                              hipStream_t stream) {
    const float* x      = (const float*)d_in[0];
    const int*   eidx   = (const int*)d_in[1];
    const float* n2v    = (const float*)d_in[2];
    const float* n2v_w  = (const float*)d_in[3];
    const float* n2v_b  = (const float*)d_in[4];
    const float* ip_w   = (const float*)d_in[5];
    const float* ip_b   = (const float*)d_in[6];
    const float* gate_w = (const float*)d_in[7];
    const float* gate_b = (const float*)d_in[8];
    const float* s0_wl  = (const float*)d_in[9];
    const float* s0_bl  = (const float*)d_in[10];
    const float* s0_wr  = (const float*)d_in[11];
    const float* s1_wl  = (const float*)d_in[12];
    const float* s1_bl  = (const float*)d_in[13];
    const float* s1_wr  = (const float*)d_in[14];
    const float* gat_w  = (const float*)d_in[15];
    const float* att_s  = (const float*)d_in[16];
    const float* att_d  = (const float*)d_in[17];
    const float* gat_b  = (const float*)d_in[18];
    const float* f_wl   = (const float*)d_in[19];
    const float* f_bl   = (const float*)d_in[20];
    const float* f_wr   = (const float*)d_in[21];

    const int* src = eidx;
    const int* dst = eidx + NE;

    // ---- workspace ----
    float*  ws     = (float*)d_ws;
    float*  invdeg = ws;                         // N
    float*  S1     = invdeg + NN;                // 64N  (h1, h3)
    float*  S2     = S1 + (size_t)NN * HD;       // 64N  (h0, h2)
    float*  SA     = S2 + (size_t)NN * HD;       // 64N  (n2vp during front; agg during SAGE)
    float*  a_s    = SA + (size_t)NN * HD;       // 2N
    float*  a_d    = a_s + (size_t)NN * 2;       // 2N
    float*  P      = a_d + (size_t)NN * 2;       // 32N
    ushort* hb     = (ushort*)(P + (size_t)NN * OUTD);  // 64N ushort (bf16 h copies)
    ushort* xhb    = hb + (size_t)NN * HD;              // 128N ushort (bf16 xh)
    int*    cnt    = (int*)(xhb + (size_t)NN * 128);    // N
    int*    rowptr = cnt + NN;                   // N+1
    int*    cursor = rowptr + NN + 1;            // N
    int*    blksum = cursor + NN;                // 128
    int*    colsrc = blksum + 128;               // NE

    float* n2vp = SA;
    float* agg  = SA;
    float* out  = (float*)d_out;

    const int BT = 256;
    dim3 b128(128), b256(BT);
    int eblk = (NE + BT - 1) / BT;
    int nblk = (NN + BT - 1) / BT;

    // ---- CSR ----
    hipMemsetAsync(cnt, 0, (size_t)NN * 4, stream);
    k_count<<<eblk, b256, 0, stream>>>(dst, cnt);
    k_scan1<<<SNBLK, b256, 0, stream>>>(cnt, rowptr, blksum);
    k_scan2<<<1, b128, 0, stream>>>(blksum);
    k_scan3<<<nblk, b256, 0, stream>>>(blksum, cnt, rowptr, cursor, invdeg);
    k_fill<<<eblk, b256, 0, stream>>>(src, dst, cursor, colsrc);

    // ---- front ----
    k_n2vp_t<<<NT, b256, 0, stream>>>(n2v, n2v_w, n2v_b, n2vp);
    k_front_t<<<NT, b256, 0, stream>>>(x, n2vp, ip_w, ip_b, gate_w, gate_b, S2, hb);

    // ---- SAGE 0: S2 -> S1 ----
    k_gather_mean<<<2048, b256, 0, stream>>>(rowptr, colsrc, invdeg, hb, agg);
    k_sage_t<<<NT, b256, 0, stream>>>(agg, S2, s0_wl, s0_bl, s0_wr, S1, hb);

    // ---- SAGE 1: S1 -> S2 ----
    k_gather_mean<<<2048, b256, 0, stream>>>(rowptr, colsrc, invdeg, hb, agg);
    k_sage_t<<<NT, b256, 0, stream>>>(agg, S1, s1_wl, s1_bl, s1_wr, S2, hb);

    // ---- GAT: S2 -> S1 ----
    k_gatxh_t<<<NT, b256, 0, stream>>>(S2, gat_w, att_s, att_d, xhb, a_s, a_d);
    k_gat_fused<<<2048, b256, 0, stream>>>(rowptr, colsrc, a_s, a_d, xhb, gat_b, S1);

    // ---- final SAGE: S1 -> out ----
    k_pfin<<<2048, b256, 0, stream>>>(S1, f_wl, P);
    k_final_fused<<<2048, b256, 0, stream>>>(rowptr, colsrc, invdeg, P, S1, f_bl, f_wr, out);
}

// Round 11
// 806.821 us; speedup vs baseline: 1.3218x; 1.0475x over previous
//
#include <hip/hip_runtime.h>
#include <math.h>

#define NN 100000
#define NE 1600000
#define DIN 256
#define HD 64
#define OUTD 32
#define EMBD 128
#define SLOPE 0.2f
#define AST 65
#define NT ((NN + 63) / 64)
#define SCHUNK 1024
#define SNBLK ((NN + SCHUNK - 1) / SCHUNK)   // 98

__device__ __forceinline__ float lrelu(float x) { return x > 0.f ? x : SLOPE * x; }
__device__ __forceinline__ ushort f2b(float f) {
    unsigned u = __float_as_uint(f);
    return (ushort)((u + 0x7FFFu + ((u >> 16) & 1u)) >> 16);  // RTNE fp32->bf16
}
__device__ __forceinline__ float b2f(ushort v) { return __uint_as_float(((unsigned)v) << 16); }

// ================= CSR build =================
__global__ void k_count(const int* __restrict__ dst, int* __restrict__ cnt) {
    int i = blockIdx.x * blockDim.x + threadIdx.x;
    if (i < NE) atomicAdd(&cnt[dst[i]], 1);
}

__global__ __launch_bounds__(256) void k_scan1(const int* __restrict__ cnt,
                                               int* __restrict__ rowptr,
                                               int* __restrict__ blksum) {
    __shared__ int ts[256];
    int base = blockIdx.x * SCHUNK + threadIdx.x * 4;
    int v0 = 0, v1 = 0, v2 = 0, v3 = 0;
    if (base < NN)     v0 = cnt[base];
    if (base + 1 < NN) v1 = cnt[base + 1];
    if (base + 2 < NN) v2 = cnt[base + 2];
    if (base + 3 < NN) v3 = cnt[base + 3];
    int s = v0 + v1 + v2 + v3;
    ts[threadIdx.x] = s;
    __syncthreads();
    for (int off = 1; off < 256; off <<= 1) {
        int w = (threadIdx.x >= off) ? ts[threadIdx.x - off] : 0;
        __syncthreads();
        ts[threadIdx.x] += w;
        __syncthreads();
    }
    int excl = ts[threadIdx.x] - s;
    if (base < NN)     rowptr[base]     = excl;
    if (base + 1 < NN) rowptr[base + 1] = excl + v0;
    if (base + 2 < NN) rowptr[base + 2] = excl + v0 + v1;
    if (base + 3 < NN) rowptr[base + 3] = excl + v0 + v1 + v2;
    if (threadIdx.x == 255) blksum[blockIdx.x] = ts[255];
}

__global__ __launch_bounds__(128) void k_scan2(int* __restrict__ blksum) {
    __shared__ int ts[128];
    int t = threadIdx.x;
    int v = (t < SNBLK) ? blksum[t] : 0;
    ts[t] = v;
    __syncthreads();
    for (int off = 1; off < 128; off <<= 1) {
        int w = (t >= off) ? ts[t - off] : 0;
        __syncthreads();
        ts[t] += w;
        __syncthreads();
    }
    if (t < SNBLK) blksum[t] = ts[t] - v;
}

__global__ void k_scan3(const int* __restrict__ blksum, const int* __restrict__ cnt,
                        int* __restrict__ rowptr, int* __restrict__ cursor,
                        float* __restrict__ invdeg) {
    int i = blockIdx.x * blockDim.x + threadIdx.x;
    if (i < NN) {
        int v = rowptr[i] + blksum[i >> 10];
        rowptr[i] = v;
        cursor[i] = v;
        invdeg[i] = 1.0f / fmaxf((float)cnt[i], 1.0f);
    }
    if (i == 0) rowptr[NN] = NE;
}

__global__ void k_fill(const int* __restrict__ src, const int* __restrict__ dst,
                       int* __restrict__ cursor, int* __restrict__ colsrc) {
    int i = blockIdx.x * blockDim.x + threadIdx.x;
    if (i >= NE) return;
    int pos = atomicAdd(&cursor[dst[i]], 1);
    colsrc[pos] = src[i];
}

// ================= tiled GEMM helpers (R5 baseline) =================
__device__ __forceinline__ void stageA(const float* __restrict__ g, int nbase, int ldg, int koff,
                                       float (*As)[AST]) {
    for (int i = threadIdx.x; i < 1024; i += 256) {
        int m = i >> 4, k4 = (i & 15) << 2;
        int row = nbase + m;
        if (row >= NN) row = NN - 1;
        float4 v = *(const float4*)&g[(size_t)row * ldg + koff + k4];
        As[m][k4] = v.x; As[m][k4 + 1] = v.y; As[m][k4 + 2] = v.z; As[m][k4 + 3] = v.w;
    }
}
__device__ __forceinline__ void stageW(const float* __restrict__ g, float* Ws) {
    for (int i = threadIdx.x; i < 1024; i += 256) ((float4*)Ws)[i] = ((const float4*)g)[i];
}
__device__ __forceinline__ void stageWcols(const float* __restrict__ g, int ldg, int coff,
                                           float* Ws) {
    for (int i = threadIdx.x; i < 1024; i += 256) {
        int r = i >> 4, c4 = (i & 15) << 2;
        *(float4*)&Ws[r * 64 + c4] = *(const float4*)&g[r * ldg + coff + c4];
    }
}
__device__ __forceinline__ void mac16(const float (*As)[AST], const float* __restrict__ Ws,
                                      float (*acc)[4], int tr, int tc) {
    const float* a0p = As[tr * 4 + 0];
    const float* a1p = As[tr * 4 + 1];
    const float* a2p = As[tr * 4 + 2];
    const float* a3p = As[tr * 4 + 3];
#pragma unroll 8
    for (int k = 0; k < 64; k++) {
        float4 w = *(const float4*)&Ws[k * 64 + tc * 4];
        float a0 = a0p[k], a1 = a1p[k], a2 = a2p[k], a3 = a3p[k];
        acc[0][0] += a0 * w.x; acc[0][1] += a0 * w.y; acc[0][2] += a0 * w.z; acc[0][3] += a0 * w.w;
        acc[1][0] += a1 * w.x; acc[1][1] += a1 * w.y; acc[1][2] += a1 * w.z; acc[1][3] += a1 * w.w;
        acc[2][0] += a2 * w.x; acc[2][1] += a2 * w.y; acc[2][2] += a2 * w.z; acc[2][3] += a2 * w.w;
        acc[3][0] += a3 * w.x; acc[3][1] += a3 * w.y; acc[3][2] += a3 * w.z; acc[3][3] += a3 * w.w;
    }
}

// ================= front =================
__global__ __launch_bounds__(256) void k_n2vp_t(const float* __restrict__ n2v,
                                                const float* __restrict__ w,
                                                const float* __restrict__ b,
                                                float* __restrict__ n2vp) {
    __shared__ float As[64][AST];
    __shared__ float Ws[64 * 64];
    int nbase = blockIdx.x * 64;
    int tc = threadIdx.x & 15, tr = threadIdx.x >> 4;
    float acc[4][4] = {};
    for (int c = 0; c < 2; c++) {
        if (c) __syncthreads();
        stageA(n2v, nbase, EMBD, c * 64, As);
        stageW(w + c * 64 * 64, Ws);
        __syncthreads();
        mac16(As, Ws, acc, tr, tc);
    }
    float b0 = b[tc * 4], b1 = b[tc * 4 + 1], b2 = b[tc * 4 + 2], b3 = b[tc * 4 + 3];
#pragma unroll
    for (int i = 0; i < 4; i++) {
        int row = nbase + tr * 4 + i;
        if (row < NN) {
            float4 o = {acc[i][0] + b0, acc[i][1] + b1, acc[i][2] + b2, acc[i][3] + b3};
            *(float4*)&n2vp[(size_t)row * HD + tc * 4] = o;
        }
    }
}

__global__ __launch_bounds__(256) void k_front_t(const float* __restrict__ x,
                                                 const float* __restrict__ n2vp,
                                                 const float* __restrict__ ip_w,
                                                 const float* __restrict__ ip_b,
                                                 const float* __restrict__ gate_w,
                                                 const float* __restrict__ gate_b,
                                                 float* __restrict__ h0,
                                                 ushort* __restrict__ h0b) {
    __shared__ float As[64][AST];
    __shared__ float Ws[64 * 64];
    int nbase = blockIdx.x * 64;
    int tc = threadIdx.x & 15, tr = threadIdx.x >> 4;
    float araw[4][4] = {}, ag[4][4] = {}, adel[4][4] = {};
    for (int c = 0; c < 4; c++) {
        if (c) __syncthreads();
        stageA(x, nbase, DIN, c * 64, As);
        stageW(ip_w + c * 64 * 64, Ws);
        __syncthreads();
        mac16(As, Ws, araw, tr, tc);
        __syncthreads();
        stageW(gate_w + c * 64 * 64, Ws);
        __syncthreads();
        mac16(As, Ws, ag, tr, tc);
    }
    __syncthreads();
    stageA(n2vp, nbase, HD, 0, As);
    stageW(ip_w + DIN * 64, Ws);
    __syncthreads();
    mac16(As, Ws, adel, tr, tc);
    __syncthreads();
    stageW(gate_w + DIN * 64, Ws);
    __syncthreads();
    mac16(As, Ws, ag, tr, tc);

    float ib0 = ip_b[tc * 4], ib1 = ip_b[tc * 4 + 1], ib2 = ip_b[tc * 4 + 2], ib3 = ip_b[tc * 4 + 3];
    float gb0 = gate_b[tc * 4], gb1 = gate_b[tc * 4 + 1], gb2 = gate_b[tc * 4 + 2], gb3 = gate_b[tc * 4 + 3];
#pragma unroll
    for (int i = 0; i < 4; i++) {
        int row = nbase + tr * 4 + i;
        if (row < NN) {
            float r0 = araw[i][0] + ib0, r1 = araw[i][1] + ib1, r2 = araw[i][2] + ib2, r3 = araw[i][3] + ib3;
            float s0 = 1.f / (1.f + __expf(-(ag[i][0] + gb0)));
            float s1 = 1.f / (1.f + __expf(-(ag[i][1] + gb1)));
            float s2 = 1.f / (1.f + __expf(-(ag[i][2] + gb2)));
            float s3 = 1.f / (1.f + __expf(-(ag[i][3] + gb3)));
            float4 o = {r0 + s0 * adel[i][0], r1 + s1 * adel[i][1],
                        r2 + s2 * adel[i][2], r3 + s3 * adel[i][3]};
            *(float4*)&h0[(size_t)row * HD + tc * 4] = o;
            ushort4 ob = {f2b(o.x), f2b(o.y), f2b(o.z), f2b(o.w)};
            *(ushort4*)&h0b[(size_t)row * HD + tc * 4] = ob;
        }
    }
}

// ================= gather mean: half-wave/edge, ushort2/lane, 2-edge unroll =================
__global__ void k_gather_mean(const int* __restrict__ rowptr, const int* __restrict__ colsrc,
                              const float* __restrict__ invdeg, const ushort* __restrict__ hb,
                              float* __restrict__ agg) {
    int t = threadIdx.x & 63;
    int lane = t & 31, half = t >> 5;
    int gw = blockIdx.x * (blockDim.x >> 6) + (threadIdx.x >> 6);
    int stride = gridDim.x * (blockDim.x >> 6);
    for (int n = gw; n < NN; n += stride) {
        int bg = rowptr[n], en = rowptr[n + 1];
        float a0 = 0.f, a1 = 0.f;
        int i = bg + half;
        for (; i + 2 < en; i += 4) {
            int sa = colsrc[i], sb = colsrc[i + 2];
            ushort2 va = *(const ushort2*)&hb[(size_t)sa * HD + lane * 2];
            ushort2 vb = *(const ushort2*)&hb[(size_t)sb * HD + lane * 2];
            a0 += b2f(va.x) + b2f(vb.x);
            a1 += b2f(va.y) + b2f(vb.y);
        }
        for (; i < en; i += 2) {
            int s = colsrc[i];
            ushort2 v = *(const ushort2*)&hb[(size_t)s * HD + lane * 2];
            a0 += b2f(v.x);
            a1 += b2f(v.y);
        }
        a0 += __shfl_xor(a0, 32);
        a1 += __shfl_xor(a1, 32);
        if (half == 0) {
            float id = invdeg[n];
            float2 o = {a0 * id, a1 * id};
            *(float2*)&agg[(size_t)n * HD + lane * 2] = o;
        }
    }
}

// ================= SAGE combine (emits fp32 + bf16 copy) =================
__global__ __launch_bounds__(256) void k_sage_t(const float* __restrict__ agg,
                                                const float* __restrict__ h,
                                                const float* __restrict__ wl,
                                                const float* __restrict__ bl,
                                                const float* __restrict__ wr,
                                                float* __restrict__ hout,
                                                ushort* __restrict__ houtb) {
    __shared__ float As[64][AST];
    __shared__ float Ws[64 * 64];
    int nbase = blockIdx.x * 64;
    int tc = threadIdx.x & 15, tr = threadIdx.x >> 4;
    float acc[4][4] = {};
    stageA(agg, nbase, HD, 0, As);
    stageW(wl, Ws);
    __syncthreads();
    mac16(As, Ws, acc, tr, tc);
    __syncthreads();
    stageA(h, nbase, HD, 0, As);
    stageW(wr, Ws);
    __syncthreads();
    mac16(As, Ws, acc, tr, tc);
    float b0 = bl[tc * 4], b1 = bl[tc * 4 + 1], b2 = bl[tc * 4 + 2], b3 = bl[tc * 4 + 3];
#pragma unroll
    for (int i = 0; i < 4; i++) {
        int row = nbase + tr * 4 + i;
        if (row < NN) {
            float4 o = {fmaxf(acc[i][0] + b0, 0.f), fmaxf(acc[i][1] + b1, 0.f),
                        fmaxf(acc[i][2] + b2, 0.f), fmaxf(acc[i][3] + b3, 0.f)};
            *(float4*)&hout[(size_t)row * HD + tc * 4] = o;
            ushort4 ob = {f2b(o.x), f2b(o.y), f2b(o.z), f2b(o.w)};
            *(ushort4*)&houtb[(size_t)row * HD + tc * 4] = ob;
        }
    }
}

// ================= GAT transform (xh emitted as bf16 only) =================
__global__ __launch_bounds__(256) void k_gatxh_t(const float* __restrict__ h,
                                                 const float* __restrict__ w,
                                                 const float* __restrict__ att_s,
                                                 const float* __restrict__ att_d,
                                                 ushort* __restrict__ xhb,
                                                 float* __restrict__ a_s,
                                                 float* __restrict__ a_d) {
    __shared__ float As[64][AST];
    __shared__ float Ws[64 * 64];
    int nbase = blockIdx.x * 64;
    int tc = threadIdx.x & 15, tr = threadIdx.x >> 4;
    stageA(h, nbase, HD, 0, As);
#pragma unroll
    for (int half = 0; half < 2; half++) {
        if (half) __syncthreads();
        stageWcols(w, 128, half * 64, Ws);
        __syncthreads();
        float acc[4][4] = {};
        mac16(As, Ws, acc, tr, tc);
        float as0 = att_s[half * 64 + tc * 4], as1 = att_s[half * 64 + tc * 4 + 1];
        float as2 = att_s[half * 64 + tc * 4 + 2], as3 = att_s[half * 64 + tc * 4 + 3];
        float ad0 = att_d[half * 64 + tc * 4], ad1 = att_d[half * 64 + tc * 4 + 1];
        float ad2 = att_d[half * 64 + tc * 4 + 2], ad3 = att_d[half * 64 + tc * 4 + 3];
#pragma unroll
        for (int i = 0; i < 4; i++) {
            int row = nbase + tr * 4 + i;
            float ps = acc[i][0] * as0 + acc[i][1] * as1 + acc[i][2] * as2 + acc[i][3] * as3;
            float pd = acc[i][0] * ad0 + acc[i][1] * ad1 + acc[i][2] * ad2 + acc[i][3] * ad3;
#pragma unroll
            for (int off = 8; off; off >>= 1) {
                ps += __shfl_xor(ps, off);
                pd += __shfl_xor(pd, off);
            }
            if (row < NN) {
                ushort4 ob = {f2b(acc[i][0]), f2b(acc[i][1]), f2b(acc[i][2]), f2b(acc[i][3])};
                *(ushort4*)&xhb[(size_t)row * 128 + half * 64 + tc * 4] = ob;
                if (tc == 0) {
                    a_s[row * 2 + half] = ps;
                    a_d[row * 2 + half] = pd;
                }
            }
        }
    }
}

// ================= GAT fused: half-wave/edge, ushort4/lane (full 128-row per inst) ======
__global__ void k_gat_fused(const int* __restrict__ rowptr, const int* __restrict__ colsrc,
                            const float* __restrict__ a_s, const float* __restrict__ a_d,
                            const ushort* __restrict__ xhb, const float* __restrict__ gb,
                            float* __restrict__ hout) {
    int t = threadIdx.x & 63;
    int lane = t & 31, half = t >> 5;
    int bl4 = (lane & 15) * 4;
    float4 bias4 = *(const float4*)&gb[bl4];
    int gw = blockIdx.x * (blockDim.x >> 6) + (threadIdx.x >> 6);
    int stride = gridDim.x * (blockDim.x >> 6);
    for (int n = gw; n < NN; n += stride) {
        int bg = rowptr[n], en = rowptr[n + 1];
        float ad0 = a_d[n * 2], ad1 = a_d[n * 2 + 1];
        float a0 = 0.f, a1 = 0.f, a2 = 0.f, a3 = 0.f;
        float ss0 = 0.f, ss1 = 0.f;
        for (int i = bg + half; i < en; i += 2) {
            int s = colsrc[i];
            float2 av = *(const float2*)&a_s[s * 2];
            float w0 = __expf(lrelu(av.x + ad0));
            float w1 = __expf(lrelu(av.y + ad1));
            ss0 += w0;
            ss1 += w1;
            float wsel = (lane < 16) ? w0 : w1;
            ushort4 xv = *(const ushort4*)&xhb[(size_t)s * 128 + lane * 4];
            a0 += wsel * b2f(xv.x);
            a1 += wsel * b2f(xv.y);
            a2 += wsel * b2f(xv.z);
            a3 += wsel * b2f(xv.w);
        }
        if (half == 0) {  // self-loop
            float2 av = *(const float2*)&a_s[n * 2];
            float w0 = __expf(lrelu(av.x + ad0));
            float w1 = __expf(lrelu(av.y + ad1));
            ss0 += w0;
            ss1 += w1;
            float wsel = (lane < 16) ? w0 : w1;
            ushort4 xv = *(const ushort4*)&xhb[(size_t)n * 128 + lane * 4];
            a0 += wsel * b2f(xv.x);
            a1 += wsel * b2f(xv.y);
            a2 += wsel * b2f(xv.z);
            a3 += wsel * b2f(xv.w);
        }
        ss0 += __shfl_xor(ss0, 32);
        ss1 += __shfl_xor(ss1, 32);
        a0 += __shfl_xor(a0, 32);
        a1 += __shfl_xor(a1, 32);
        a2 += __shfl_xor(a2, 32);
        a3 += __shfl_xor(a3, 32);
        float r = (lane < 16) ? (0.5f / (ss0 + 1e-16f)) : (0.5f / (ss1 + 1e-16f));
        float v0 = a0 * r, v1 = a1 * r, v2 = a2 * r, v3 = a3 * r;
        float p0 = __shfl_xor(v0, 16);
        float p1 = __shfl_xor(v1, 16);
        float p2 = __shfl_xor(v2, 16);
        float p3 = __shfl_xor(v3, 16);
        if (half == 0 && lane < 16) {
            float4 o = {fmaxf(v0 + p0 + bias4.x, 0.f), fmaxf(v1 + p1 + bias4.y, 0.f),
                        fmaxf(v2 + p2 + bias4.z, 0.f), fmaxf(v3 + p3 + bias4.w, 0.f)};
            *(float4*)&hout[(size_t)n * HD + lane * 4] = o;
        }
    }
}

// ================= final SAGE: P in bf16 =================
__global__ void k_pfin(const float* __restrict__ h, const float* __restrict__ wl,
                       ushort* __restrict__ Pb) {
    __shared__ float sw[HD * OUTD];
    for (int i = threadIdx.x; i < HD * OUTD; i += blockDim.x) sw[i] = wl[i];
    __syncthreads();
    int t = threadIdx.x & 63;
    int c = t & 31, half = t >> 5;
    int gw = blockIdx.x * (blockDim.x >> 6) + (threadIdx.x >> 6);
    int stride = gridDim.x * (blockDim.x >> 6);
    for (int n = gw; n < NN; n += stride) {
        float hv = h[(size_t)n * HD + t];
        float acc = 0.f;
#pragma unroll 8
        for (int i = 0; i < 32; i++) {
            float bb = __shfl(hv, half * 32 + i);
            acc += bb * sw[half * 1024 + i * 32 + c];
        }
        acc += __shfl_xor(acc, 32);
        if (half == 0) Pb[(size_t)n * OUTD + c] = f2b(acc);
    }
}

// quarter-wave per edge: 16 lanes x ushort2 covers one 32-wide bf16 P row
__global__ void k_final_fused(const int* __restrict__ rowptr, const int* __restrict__ colsrc,
                              const float* __restrict__ invdeg, const ushort* __restrict__ Pb,
                              const float* __restrict__ h, const float* __restrict__ bl,
                              const float* __restrict__ wr, float* __restrict__ out) {
    __shared__ float sw[HD * OUTD];
    for (int i = threadIdx.x; i < HD * OUTD; i += blockDim.x) sw[i] = wr[i];
    __syncthreads();
    int t = threadIdx.x & 63;
    int j = t & 31, half = t >> 5;
    int quarter = t >> 4, lane16 = t & 15;
    float bias = bl[j];
    int gw = blockIdx.x * (blockDim.x >> 6) + (threadIdx.x >> 6);
    int stride = gridDim.x * (blockDim.x >> 6);
    for (int n = gw; n < NN; n += stride) {
        int bg = rowptr[n], en = rowptr[n + 1];
        // gather (quarter-wave per edge, bf16)
        float a0 = 0.f, a1 = 0.f;
        for (int i = bg + quarter; i < en; i += 4) {
            int s = colsrc[i];
            ushort2 v = *(const ushort2*)&Pb[(size_t)s * OUTD + lane16 * 2];
            a0 += b2f(v.x);
            a1 += b2f(v.y);
        }
        a0 += __shfl_xor(a0, 32);
        a1 += __shfl_xor(a1, 32);
        a0 += __shfl_xor(a0, 16);
        a1 += __shfl_xor(a1, 16);
        // dense h3 @ f_wr for col j
        float hv = h[(size_t)n * HD + t];
        float o = 0.f;
#pragma unroll 8
        for (int i2 = 0; i2 < 32; i2++) {
            float bb = __shfl(hv, half * 32 + i2);
            o += bb * sw[half * 1024 + i2 * 32 + j];
        }
        o += __shfl_xor(o, 32);
        // redistribute gathered col j: source lane (j>>1) holds cols (j&~1, j|1)
        float ga = __shfl(a0, j >> 1);
        float gb_ = __shfl(a1, j >> 1);
        float gv = (j & 1) ? gb_ : ga;
        if (half == 0) out[(size_t)n * OUTD + j] = gv * invdeg[n] + bias + o;
    }
}

// ================= launch =================
extern "C" void kernel_launch(void* const* d_in, const int* in_sizes, int n_in,
                              void* d_out, int out_size, void* d_ws, size_t ws_size,
                              hipStream_t stream) {
    const float* x      = (const float*)d_in[0];
    const int*   eidx   = (const int*)d_in[1];
    const float* n2v    = (const float*)d_in[2];
    const float* n2v_w  = (const float*)d_in[3];
    const float* n2v_b  = (const float*)d_in[4];
    const float* ip_w   = (const float*)d_in[5];
    const float* ip_b   = (const float*)d_in[6];
    const float* gate_w = (const float*)d_in[7];
    const float* gate_b = (const float*)d_in[8];
    const float* s0_wl  = (const float*)d_in[9];
    const float* s0_bl  = (const float*)d_in[10];
    const float* s0_wr  = (const float*)d_in[11];
    const float* s1_wl  = (const float*)d_in[12];
    const float* s1_bl  = (const float*)d_in[13];
    const float* s1_wr  = (const float*)d_in[14];
    const float* gat_w  = (const float*)d_in[15];
    const float* att_s  = (const float*)d_in[16];
    const float* att_d  = (const float*)d_in[17];
    const float* gat_b  = (const float*)d_in[18];
    const float* f_wl   = (const float*)d_in[19];
    const float* f_bl   = (const float*)d_in[20];
    const float* f_wr   = (const float*)d_in[21];

    const int* src = eidx;
    const int* dst = eidx + NE;

    // ---- workspace ----
    float*  ws     = (float*)d_ws;
    float*  invdeg = ws;                         // N
    float*  S1     = invdeg + NN;                // 64N  (h1, h3)
    float*  S2     = S1 + (size_t)NN * HD;       // 64N  (h0, h2)
    float*  SA     = S2 + (size_t)NN * HD;       // 64N  (n2vp / agg)
    float*  a_s    = SA + (size_t)NN * HD;       // 2N
    float*  a_d    = a_s + (size_t)NN * 2;       // 2N
    ushort* Pb     = (ushort*)(a_d + (size_t)NN * 2);   // 32N ushort
    ushort* hb     = Pb + (size_t)NN * OUTD;            // 64N ushort
    ushort* xhb    = hb + (size_t)NN * HD;              // 128N ushort
    int*    cnt    = (int*)(xhb + (size_t)NN * 128);    // N
    int*    rowptr = cnt + NN;                   // N+1
    int*    cursor = rowptr + NN + 1;            // N
    int*    blksum = cursor + NN;                // 128
    int*    colsrc = blksum + 128;               // NE

    float* n2vp = SA;
    float* agg  = SA;
    float* out  = (float*)d_out;

    const int BT = 256;
    dim3 b128(128), b256(BT);
    int eblk = (NE + BT - 1) / BT;
    int nblk = (NN + BT - 1) / BT;

    // ---- CSR ----
    hipMemsetAsync(cnt, 0, (size_t)NN * 4, stream);
    k_count<<<eblk, b256, 0, stream>>>(dst, cnt);
    k_scan1<<<SNBLK, b256, 0, stream>>>(cnt, rowptr, blksum);
    k_scan2<<<1, b128, 0, stream>>>(blksum);
    k_scan3<<<nblk, b256, 0, stream>>>(blksum, cnt, rowptr, cursor, invdeg);
    k_fill<<<eblk, b256, 0, stream>>>(src, dst, cursor, colsrc);

    // ---- front ----
    k_n2vp_t<<<NT, b256, 0, stream>>>(n2v, n2v_w, n2v_b, n2vp);
    k_front_t<<<NT, b256, 0, stream>>>(x, n2vp, ip_w, ip_b, gate_w, gate_b, S2, hb);

    // ---- SAGE 0: S2 -> S1 ----
    k_gather_mean<<<2048, b256, 0, stream>>>(rowptr, colsrc, invdeg, hb, agg);
    k_sage_t<<<NT, b256, 0, stream>>>(agg, S2, s0_wl, s0_bl, s0_wr, S1, hb);

    // ---- SAGE 1: S1 -> S2 ----
    k_gather_mean<<<2048, b256, 0, stream>>>(rowptr, colsrc, invdeg, hb, agg);
    k_sage_t<<<NT, b256, 0, stream>>>(agg, S1, s1_wl, s1_bl, s1_wr, S2, hb);

    // ---- GAT: S2 -> S1 ----
    k_gatxh_t<<<NT, b256, 0, stream>>>(S2, gat_w, att_s, att_d, xhb, a_s, a_d);
    k_gat_fused<<<2048, b256, 0, stream>>>(rowptr, colsrc, a_s, a_d, xhb, gat_b, S1);

    // ---- final SAGE: S1 -> out ----
    k_pfin<<<2048, b256, 0, stream>>>(S1, f_wl, Pb);
    k_final_fused<<<2048, b256, 0, stream>>>(rowptr, colsrc, invdeg, Pb, S1, f_bl, f_wr, out);
}

// Round 12
// 758.010 us; speedup vs baseline: 1.4069x; 1.0644x over previous
//
#include <hip/hip_runtime.h>
#include <math.h>

#define NN 100000
#define NE 1600000
#define DIN 256
#define HD 64
#define OUTD 32
#define EMBD 128
#define SLOPE 0.2f
#define AST 68
#define NT ((NN + 63) / 64)
#define SCHUNK 1024
#define SNBLK ((NN + SCHUNK - 1) / SCHUNK)   // 98

__device__ __forceinline__ float lrelu(float x) { return x > 0.f ? x : SLOPE * x; }
__device__ __forceinline__ ushort f2b(float f) {
    unsigned u = __float_as_uint(f);
    return (ushort)((u + 0x7FFFu + ((u >> 16) & 1u)) >> 16);  // RTNE fp32->bf16
}
__device__ __forceinline__ float b2f(ushort v) { return __uint_as_float(((unsigned)v) << 16); }

// ================= CSR build =================
__global__ void k_count(const int* __restrict__ dst, int* __restrict__ cnt) {
    int i = blockIdx.x * blockDim.x + threadIdx.x;
    if (i < NE) atomicAdd(&cnt[dst[i]], 1);
}

__global__ __launch_bounds__(256) void k_scan1(const int* __restrict__ cnt,
                                               int* __restrict__ rowptr,
                                               int* __restrict__ blksum) {
    __shared__ int ts[256];
    int base = blockIdx.x * SCHUNK + threadIdx.x * 4;
    int v0 = 0, v1 = 0, v2 = 0, v3 = 0;
    if (base < NN)     v0 = cnt[base];
    if (base + 1 < NN) v1 = cnt[base + 1];
    if (base + 2 < NN) v2 = cnt[base + 2];
    if (base + 3 < NN) v3 = cnt[base + 3];
    int s = v0 + v1 + v2 + v3;
    ts[threadIdx.x] = s;
    __syncthreads();
    for (int off = 1; off < 256; off <<= 1) {
        int w = (threadIdx.x >= off) ? ts[threadIdx.x - off] : 0;
        __syncthreads();
        ts[threadIdx.x] += w;
        __syncthreads();
    }
    int excl = ts[threadIdx.x] - s;
    if (base < NN)     rowptr[base]     = excl;
    if (base + 1 < NN) rowptr[base + 1] = excl + v0;
    if (base + 2 < NN) rowptr[base + 2] = excl + v0 + v1;
    if (base + 3 < NN) rowptr[base + 3] = excl + v0 + v1 + v2;
    if (threadIdx.x == 255) blksum[blockIdx.x] = ts[255];
}

__global__ __launch_bounds__(128) void k_scan2(int* __restrict__ blksum) {
    __shared__ int ts[128];
    int t = threadIdx.x;
    int v = (t < SNBLK) ? blksum[t] : 0;
    ts[t] = v;
    __syncthreads();
    for (int off = 1; off < 128; off <<= 1) {
        int w = (t >= off) ? ts[t - off] : 0;
        __syncthreads();
        ts[t] += w;
        __syncthreads();
    }
    if (t < SNBLK) blksum[t] = ts[t] - v;
}

__global__ void k_scan3(const int* __restrict__ blksum, const int* __restrict__ cnt,
                        int* __restrict__ rowptr, int* __restrict__ cursor,
                        float* __restrict__ invdeg) {
    int i = blockIdx.x * blockDim.x + threadIdx.x;
    if (i < NN) {
        int v = rowptr[i] + blksum[i >> 10];
        rowptr[i] = v;
        cursor[i] = v;
        invdeg[i] = 1.0f / fmaxf((float)cnt[i], 1.0f);
    }
    if (i == 0) rowptr[NN] = NE;
}

__global__ void k_fill(const int* __restrict__ src, const int* __restrict__ dst,
                       int* __restrict__ cursor, int* __restrict__ colsrc) {
    int i = blockIdx.x * blockDim.x + threadIdx.x;
    if (i >= NE) return;
    int pos = atomicAdd(&cursor[dst[i]], 1);
    colsrc[pos] = src[i];
}

// ================= tiled GEMM helpers (vector A-reads, AST=68) =================
__device__ __forceinline__ void stageA(const float* __restrict__ g, int nbase, int ldg, int koff,
                                       float (*As)[AST]) {
    for (int i = threadIdx.x; i < 1024; i += 256) {
        int m = i >> 4, k4 = (i & 15) << 2;
        int row = nbase + m;
        if (row >= NN) row = NN - 1;
        *(float4*)&As[m][k4] = *(const float4*)&g[(size_t)row * ldg + koff + k4];
    }
}
__device__ __forceinline__ void stageW(const float* __restrict__ g, float* Ws) {
    for (int i = threadIdx.x; i < 1024; i += 256) ((float4*)Ws)[i] = ((const float4*)g)[i];
}
__device__ __forceinline__ void stageWcols(const float* __restrict__ g, int ldg, int coff,
                                           float* Ws) {
    for (int i = threadIdx.x; i < 1024; i += 256) {
        int r = i >> 4, c4 = (i & 15) << 2;
        *(float4*)&Ws[r * 64 + c4] = *(const float4*)&g[r * ldg + coff + c4];
    }
}
// acc[4][4] += A[tr*4+i][k] * W[k][tc*4+j]; A read as float4 (b128)
__device__ __forceinline__ void mac16v(const float (*As)[AST], const float* __restrict__ Ws,
                                       float (*acc)[4], int tr, int tc) {
#pragma unroll 4
    for (int k4 = 0; k4 < 64; k4 += 4) {
        float4 a0 = *(const float4*)&As[tr * 4 + 0][k4];
        float4 a1 = *(const float4*)&As[tr * 4 + 1][k4];
        float4 a2 = *(const float4*)&As[tr * 4 + 2][k4];
        float4 a3 = *(const float4*)&As[tr * 4 + 3][k4];
#pragma unroll
        for (int j = 0; j < 4; j++) {
            float4 w = *(const float4*)&Ws[(k4 + j) * 64 + tc * 4];
            float e0 = (&a0.x)[j], e1 = (&a1.x)[j], e2 = (&a2.x)[j], e3 = (&a3.x)[j];
            acc[0][0] += e0 * w.x; acc[0][1] += e0 * w.y; acc[0][2] += e0 * w.z; acc[0][3] += e0 * w.w;
            acc[1][0] += e1 * w.x; acc[1][1] += e1 * w.y; acc[1][2] += e1 * w.z; acc[1][3] += e1 * w.w;
            acc[2][0] += e2 * w.x; acc[2][1] += e2 * w.y; acc[2][2] += e2 * w.z; acc[2][3] += e2 * w.w;
            acc[3][0] += e3 * w.x; acc[3][1] += e3 * w.y; acc[3][2] += e3 * w.z; acc[3][3] += e3 * w.w;
        }
    }
}

// ================= front =================
__global__ __launch_bounds__(256) void k_n2vp_t(const float* __restrict__ n2v,
                                                const float* __restrict__ w,
                                                const float* __restrict__ b,
                                                float* __restrict__ n2vp) {
    __shared__ float As[64][AST];
    __shared__ float Ws[64 * 64];
    int nbase = blockIdx.x * 64;
    int tc = threadIdx.x & 15, tr = threadIdx.x >> 4;
    float acc[4][4] = {};
    for (int c = 0; c < 2; c++) {
        if (c) __syncthreads();
        stageA(n2v, nbase, EMBD, c * 64, As);
        stageW(w + c * 64 * 64, Ws);
        __syncthreads();
        mac16v(As, Ws, acc, tr, tc);
    }
    float b0 = b[tc * 4], b1 = b[tc * 4 + 1], b2 = b[tc * 4 + 2], b3 = b[tc * 4 + 3];
#pragma unroll
    for (int i = 0; i < 4; i++) {
        int row = nbase + tr * 4 + i;
        if (row < NN) {
            float4 o = {acc[i][0] + b0, acc[i][1] + b1, acc[i][2] + b2, acc[i][3] + b3};
            *(float4*)&n2vp[(size_t)row * HD + tc * 4] = o;
        }
    }
}

__global__ __launch_bounds__(256) void k_front_t(const float* __restrict__ x,
                                                 const float* __restrict__ n2vp,
                                                 const float* __restrict__ ip_w,
                                                 const float* __restrict__ ip_b,
                                                 const float* __restrict__ gate_w,
                                                 const float* __restrict__ gate_b,
                                                 float* __restrict__ h0,
                                                 ushort* __restrict__ h0b) {
    __shared__ float As[64][AST];
    __shared__ float Ws[64 * 64];
    int nbase = blockIdx.x * 64;
    int tc = threadIdx.x & 15, tr = threadIdx.x >> 4;
    float araw[4][4] = {}, ag[4][4] = {}, adel[4][4] = {};
    for (int c = 0; c < 4; c++) {
        if (c) __syncthreads();
        stageA(x, nbase, DIN, c * 64, As);
        stageW(ip_w + c * 64 * 64, Ws);
        __syncthreads();
        mac16v(As, Ws, araw, tr, tc);
        __syncthreads();
        stageW(gate_w + c * 64 * 64, Ws);
        __syncthreads();
        mac16v(As, Ws, ag, tr, tc);
    }
    __syncthreads();
    stageA(n2vp, nbase, HD, 0, As);
    stageW(ip_w + DIN * 64, Ws);
    __syncthreads();
    mac16v(As, Ws, adel, tr, tc);
    __syncthreads();
    stageW(gate_w + DIN * 64, Ws);
    __syncthreads();
    mac16v(As, Ws, ag, tr, tc);

    float ib0 = ip_b[tc * 4], ib1 = ip_b[tc * 4 + 1], ib2 = ip_b[tc * 4 + 2], ib3 = ip_b[tc * 4 + 3];
    float gb0 = gate_b[tc * 4], gb1 = gate_b[tc * 4 + 1], gb2 = gate_b[tc * 4 + 2], gb3 = gate_b[tc * 4 + 3];
#pragma unroll
    for (int i = 0; i < 4; i++) {
        int row = nbase + tr * 4 + i;
        if (row < NN) {
            float r0 = araw[i][0] + ib0, r1 = araw[i][1] + ib1, r2 = araw[i][2] + ib2, r3 = araw[i][3] + ib3;
            float s0 = 1.f / (1.f + __expf(-(ag[i][0] + gb0)));
            float s1 = 1.f / (1.f + __expf(-(ag[i][1] + gb1)));
            float s2 = 1.f / (1.f + __expf(-(ag[i][2] + gb2)));
            float s3 = 1.f / (1.f + __expf(-(ag[i][3] + gb3)));
            float4 o = {r0 + s0 * adel[i][0], r1 + s1 * adel[i][1],
                        r2 + s2 * adel[i][2], r3 + s3 * adel[i][3]};
            *(float4*)&h0[(size_t)row * HD + tc * 4] = o;
            ushort4 ob = {f2b(o.x), f2b(o.y), f2b(o.z), f2b(o.w)};
            *(ushort4*)&h0b[(size_t)row * HD + tc * 4] = ob;
        }
    }
}

// ================= gather mean: half-wave/edge, ushort2/lane, 4-edge unroll =================
__global__ void k_gather_mean(const int* __restrict__ rowptr, const int* __restrict__ colsrc,
                              const float* __restrict__ invdeg, const ushort* __restrict__ hb,
                              float* __restrict__ agg) {
    int t = threadIdx.x & 63;
    int lane = t & 31, half = t >> 5;
    int gw = blockIdx.x * (blockDim.x >> 6) + (threadIdx.x >> 6);
    int stride = gridDim.x * (blockDim.x >> 6);
    for (int n = gw; n < NN; n += stride) {
        int bg = rowptr[n], en = rowptr[n + 1];
        float a0 = 0.f, a1 = 0.f;
        int i = bg + half;
        for (; i + 6 < en; i += 8) {
            int sa = colsrc[i], sb = colsrc[i + 2], sc = colsrc[i + 4], sd = colsrc[i + 6];
            ushort2 va = *(const ushort2*)&hb[(size_t)sa * HD + lane * 2];
            ushort2 vb = *(const ushort2*)&hb[(size_t)sb * HD + lane * 2];
            ushort2 vc = *(const ushort2*)&hb[(size_t)sc * HD + lane * 2];
            ushort2 vd = *(const ushort2*)&hb[(size_t)sd * HD + lane * 2];
            a0 += b2f(va.x) + b2f(vb.x) + b2f(vc.x) + b2f(vd.x);
            a1 += b2f(va.y) + b2f(vb.y) + b2f(vc.y) + b2f(vd.y);
        }
        for (; i < en; i += 2) {
            int s = colsrc[i];
            ushort2 v = *(const ushort2*)&hb[(size_t)s * HD + lane * 2];
            a0 += b2f(v.x);
            a1 += b2f(v.y);
        }
        a0 += __shfl_xor(a0, 32);
        a1 += __shfl_xor(a1, 32);
        if (half == 0) {
            float id = invdeg[n];
            float2 o = {a0 * id, a1 * id};
            *(float2*)&agg[(size_t)n * HD + lane * 2] = o;
        }
    }
}

// ================= SAGE combine (emits fp32 + bf16 copy) =================
__global__ __launch_bounds__(256) void k_sage_t(const float* __restrict__ agg,
                                                const float* __restrict__ h,
                                                const float* __restrict__ wl,
                                                const float* __restrict__ bl,
                                                const float* __restrict__ wr,
                                                float* __restrict__ hout,
                                                ushort* __restrict__ houtb) {
    __shared__ float As[64][AST];
    __shared__ float Ws[64 * 64];
    int nbase = blockIdx.x * 64;
    int tc = threadIdx.x & 15, tr = threadIdx.x >> 4;
    float acc[4][4] = {};
    stageA(agg, nbase, HD, 0, As);
    stageW(wl, Ws);
    __syncthreads();
    mac16v(As, Ws, acc, tr, tc);
    __syncthreads();
    stageA(h, nbase, HD, 0, As);
    stageW(wr, Ws);
    __syncthreads();
    mac16v(As, Ws, acc, tr, tc);
    float b0 = bl[tc * 4], b1 = bl[tc * 4 + 1], b2 = bl[tc * 4 + 2], b3 = bl[tc * 4 + 3];
#pragma unroll
    for (int i = 0; i < 4; i++) {
        int row = nbase + tr * 4 + i;
        if (row < NN) {
            float4 o = {fmaxf(acc[i][0] + b0, 0.f), fmaxf(acc[i][1] + b1, 0.f),
                        fmaxf(acc[i][2] + b2, 0.f), fmaxf(acc[i][3] + b3, 0.f)};
            *(float4*)&hout[(size_t)row * HD + tc * 4] = o;
            ushort4 ob = {f2b(o.x), f2b(o.y), f2b(o.z), f2b(o.w)};
            *(ushort4*)&houtb[(size_t)row * HD + tc * 4] = ob;
        }
    }
}

// ================= GAT transform (xh emitted as bf16 only) =================
__global__ __launch_bounds__(256) void k_gatxh_t(const float* __restrict__ h,
                                                 const float* __restrict__ w,
                                                 const float* __restrict__ att_s,
                                                 const float* __restrict__ att_d,
                                                 ushort* __restrict__ xhb,
                                                 float* __restrict__ a_s,
                                                 float* __restrict__ a_d) {
    __shared__ float As[64][AST];
    __shared__ float Ws[64 * 64];
    int nbase = blockIdx.x * 64;
    int tc = threadIdx.x & 15, tr = threadIdx.x >> 4;
    stageA(h, nbase, HD, 0, As);
#pragma unroll
    for (int half = 0; half < 2; half++) {
        if (half) __syncthreads();
        stageWcols(w, 128, half * 64, Ws);
        __syncthreads();
        float acc[4][4] = {};
        mac16v(As, Ws, acc, tr, tc);
        float as0 = att_s[half * 64 + tc * 4], as1 = att_s[half * 64 + tc * 4 + 1];
        float as2 = att_s[half * 64 + tc * 4 + 2], as3 = att_s[half * 64 + tc * 4 + 3];
        float ad0 = att_d[half * 64 + tc * 4], ad1 = att_d[half * 64 + tc * 4 + 1];
        float ad2 = att_d[half * 64 + tc * 4 + 2], ad3 = att_d[half * 64 + tc * 4 + 3];
#pragma unroll
        for (int i = 0; i < 4; i++) {
            int row = nbase + tr * 4 + i;
            float ps = acc[i][0] * as0 + acc[i][1] * as1 + acc[i][2] * as2 + acc[i][3] * as3;
            float pd = acc[i][0] * ad0 + acc[i][1] * ad1 + acc[i][2] * ad2 + acc[i][3] * ad3;
#pragma unroll
            for (int off = 8; off; off >>= 1) {
                ps += __shfl_xor(ps, off);
                pd += __shfl_xor(pd, off);
            }
            if (row < NN) {
                ushort4 ob = {f2b(acc[i][0]), f2b(acc[i][1]), f2b(acc[i][2]), f2b(acc[i][3])};
                *(ushort4*)&xhb[(size_t)row * 128 + half * 64 + tc * 4] = ob;
                if (tc == 0) {
                    a_s[row * 2 + half] = ps;
                    a_d[row * 2 + half] = pd;
                }
            }
        }
    }
}

// ================= GAT fused: half-wave/edge, ushort4/lane, 2-edge unroll =================
__global__ void k_gat_fused(const int* __restrict__ rowptr, const int* __restrict__ colsrc,
                            const float* __restrict__ a_s, const float* __restrict__ a_d,
                            const ushort* __restrict__ xhb, const float* __restrict__ gb,
                            float* __restrict__ hout) {
    int t = threadIdx.x & 63;
    int lane = t & 31, half = t >> 5;
    int bl4 = (lane & 15) * 4;
    float4 bias4 = *(const float4*)&gb[bl4];
    int gw = blockIdx.x * (blockDim.x >> 6) + (threadIdx.x >> 6);
    int stride = gridDim.x * (blockDim.x >> 6);
    for (int n = gw; n < NN; n += stride) {
        int bg = rowptr[n], en = rowptr[n + 1];
        float ad0 = a_d[n * 2], ad1 = a_d[n * 2 + 1];
        float a0 = 0.f, a1 = 0.f, a2 = 0.f, a3 = 0.f;
        float ss0 = 0.f, ss1 = 0.f;
        int i = bg + half;
        for (; i + 2 < en; i += 4) {
            int sa = colsrc[i], sb = colsrc[i + 2];
            float2 ava = *(const float2*)&a_s[sa * 2];
            float2 avb = *(const float2*)&a_s[sb * 2];
            ushort4 xva = *(const ushort4*)&xhb[(size_t)sa * 128 + lane * 4];
            ushort4 xvb = *(const ushort4*)&xhb[(size_t)sb * 128 + lane * 4];
            float wa0 = __expf(lrelu(ava.x + ad0));
            float wa1 = __expf(lrelu(ava.y + ad1));
            float wb0 = __expf(lrelu(avb.x + ad0));
            float wb1 = __expf(lrelu(avb.y + ad1));
            ss0 += wa0 + wb0;
            ss1 += wa1 + wb1;
            float wsa = (lane < 16) ? wa0 : wa1;
            float wsb = (lane < 16) ? wb0 : wb1;
            a0 += wsa * b2f(xva.x) + wsb * b2f(xvb.x);
            a1 += wsa * b2f(xva.y) + wsb * b2f(xvb.y);
            a2 += wsa * b2f(xva.z) + wsb * b2f(xvb.z);
            a3 += wsa * b2f(xva.w) + wsb * b2f(xvb.w);
        }
        for (; i < en; i += 2) {
            int s = colsrc[i];
            float2 av = *(const float2*)&a_s[s * 2];
            float w0 = __expf(lrelu(av.x + ad0));
            float w1 = __expf(lrelu(av.y + ad1));
            ss0 += w0;
            ss1 += w1;
            float wsel = (lane < 16) ? w0 : w1;
            ushort4 xv = *(const ushort4*)&xhb[(size_t)s * 128 + lane * 4];
            a0 += wsel * b2f(xv.x);
            a1 += wsel * b2f(xv.y);
            a2 += wsel * b2f(xv.z);
            a3 += wsel * b2f(xv.w);
        }
        if (half == 0) {  // self-loop
            float2 av = *(const float2*)&a_s[n * 2];
            float w0 = __expf(lrelu(av.x + ad0));
            float w1 = __expf(lrelu(av.y + ad1));
            ss0 += w0;
            ss1 += w1;
            float wsel = (lane < 16) ? w0 : w1;
            ushort4 xv = *(const ushort4*)&xhb[(size_t)n * 128 + lane * 4];
            a0 += wsel * b2f(xv.x);
            a1 += wsel * b2f(xv.y);
            a2 += wsel * b2f(xv.z);
            a3 += wsel * b2f(xv.w);
        }
        ss0 += __shfl_xor(ss0, 32);
        ss1 += __shfl_xor(ss1, 32);
        a0 += __shfl_xor(a0, 32);
        a1 += __shfl_xor(a1, 32);
        a2 += __shfl_xor(a2, 32);
        a3 += __shfl_xor(a3, 32);
        float r = (lane < 16) ? (0.5f / (ss0 + 1e-16f)) : (0.5f / (ss1 + 1e-16f));
        float v0 = a0 * r, v1 = a1 * r, v2 = a2 * r, v3 = a3 * r;
        float p0 = __shfl_xor(v0, 16);
        float p1 = __shfl_xor(v1, 16);
        float p2 = __shfl_xor(v2, 16);
        float p3 = __shfl_xor(v3, 16);
        if (half == 0 && lane < 16) {
            float4 o = {fmaxf(v0 + p0 + bias4.x, 0.f), fmaxf(v1 + p1 + bias4.y, 0.f),
                        fmaxf(v2 + p2 + bias4.z, 0.f), fmaxf(v3 + p3 + bias4.w, 0.f)};
            *(float4*)&hout[(size_t)n * HD + lane * 4] = o;
        }
    }
}

// ================= final SAGE: P in bf16 =================
__global__ void k_pfin(const float* __restrict__ h, const float* __restrict__ wl,
                       ushort* __restrict__ Pb) {
    __shared__ float sw[HD * OUTD];
    for (int i = threadIdx.x; i < HD * OUTD; i += blockDim.x) sw[i] = wl[i];
    __syncthreads();
    int t = threadIdx.x & 63;
    int c = t & 31, half = t >> 5;
    int gw = blockIdx.x * (blockDim.x >> 6) + (threadIdx.x >> 6);
    int stride = gridDim.x * (blockDim.x >> 6);
    for (int n = gw; n < NN; n += stride) {
        float hv = h[(size_t)n * HD + t];
        float acc = 0.f;
#pragma unroll 8
        for (int i = 0; i < 32; i++) {
            float bb = __shfl(hv, half * 32 + i);
            acc += bb * sw[half * 1024 + i * 32 + c];
        }
        acc += __shfl_xor(acc, 32);
        if (half == 0) Pb[(size_t)n * OUTD + c] = f2b(acc);
    }
}

// quarter-wave per edge, 2-edge unroll
__global__ void k_final_fused(const int* __restrict__ rowptr, const int* __restrict__ colsrc,
                              const float* __restrict__ invdeg, const ushort* __restrict__ Pb,
                              const float* __restrict__ h, const float* __restrict__ bl,
                              const float* __restrict__ wr, float* __restrict__ out) {
    __shared__ float sw[HD * OUTD];
    for (int i = threadIdx.x; i < HD * OUTD; i += blockDim.x) sw[i] = wr[i];
    __syncthreads();
    int t = threadIdx.x & 63;
    int j = t & 31, half = t >> 5;
    int quarter = t >> 4, lane16 = t & 15;
    float bias = bl[j];
    int gw = blockIdx.x * (blockDim.x >> 6) + (threadIdx.x >> 6);
    int stride = gridDim.x * (blockDim.x >> 6);
    for (int n = gw; n < NN; n += stride) {
        int bg = rowptr[n], en = rowptr[n + 1];
        float a0 = 0.f, a1 = 0.f;
        int i = bg + quarter;
        for (; i + 4 < en; i += 8) {
            int sa = colsrc[i], sb = colsrc[i + 4];
            ushort2 va = *(const ushort2*)&Pb[(size_t)sa * OUTD + lane16 * 2];
            ushort2 vb = *(const ushort2*)&Pb[(size_t)sb * OUTD + lane16 * 2];
            a0 += b2f(va.x) + b2f(vb.x);
            a1 += b2f(va.y) + b2f(vb.y);
        }
        for (; i < en; i += 4) {
            int s = colsrc[i];
            ushort2 v = *(const ushort2*)&Pb[(size_t)s * OUTD + lane16 * 2];
            a0 += b2f(v.x);
            a1 += b2f(v.y);
        }
        a0 += __shfl_xor(a0, 32);
        a1 += __shfl_xor(a1, 32);
        a0 += __shfl_xor(a0, 16);
        a1 += __shfl_xor(a1, 16);
        float hv = h[(size_t)n * HD + t];
        float o = 0.f;
#pragma unroll 8
        for (int i2 = 0; i2 < 32; i2++) {
            float bb = __shfl(hv, half * 32 + i2);
            o += bb * sw[half * 1024 + i2 * 32 + j];
        }
        o += __shfl_xor(o, 32);
        float ga = __shfl(a0, j >> 1);
        float gb_ = __shfl(a1, j >> 1);
        float gv = (j & 1) ? gb_ : ga;
        if (half == 0) out[(size_t)n * OUTD + j] = gv * invdeg[n] + bias + o;
    }
}

// ================= launch =================
extern "C" void kernel_launch(void* const* d_in, const int* in_sizes, int n_in,
                              void* d_out, int out_size, void* d_ws, size_t ws_size,
                              hipStream_t stream) {
    const float* x      = (const float*)d_in[0];
    const int*   eidx   = (const int*)d_in[1];
    const float* n2v    = (const float*)d_in[2];
    const float* n2v_w  = (const float*)d_in[3];
    const float* n2v_b  = (const float*)d_in[4];
    const float* ip_w   = (const float*)d_in[5];
    const float* ip_b   = (const float*)d_in[6];
    const float* gate_w = (const float*)d_in[7];
    const float* gate_b = (const float*)d_in[8];
    const float* s0_wl  = (const float*)d_in[9];
    const float* s0_bl  = (const float*)d_in[10];
    const float* s0_wr  = (const float*)d_in[11];
    const float* s1_wl  = (const float*)d_in[12];
    const float* s1_bl  = (const float*)d_in[13];
    const float* s1_wr  = (const float*)d_in[14];
    const float* gat_w  = (const float*)d_in[15];
    const float* att_s  = (const float*)d_in[16];
    const float* att_d  = (const float*)d_in[17];
    const float* gat_b  = (const float*)d_in[18];
    const float* f_wl   = (const float*)d_in[19];
    const float* f_bl   = (const float*)d_in[20];
    const float* f_wr   = (const float*)d_in[21];

    const int* src = eidx;
    const int* dst = eidx + NE;

    // ---- workspace ----
    float*  ws     = (float*)d_ws;
    float*  invdeg = ws;                         // N
    float*  S1     = invdeg + NN;                // 64N  (h1, h3)
    float*  S2     = S1 + (size_t)NN * HD;       // 64N  (h0, h2)
    float*  SA     = S2 + (size_t)NN * HD;       // 64N  (n2vp / agg)
    float*  a_s    = SA + (size_t)NN * HD;       // 2N
    float*  a_d    = a_s + (size_t)NN * 2;       // 2N
    ushort* Pb     = (ushort*)(a_d + (size_t)NN * 2);   // 32N ushort
    ushort* hb     = Pb + (size_t)NN * OUTD;            // 64N ushort
    ushort* xhb    = hb + (size_t)NN * HD;              // 128N ushort
    int*    cnt    = (int*)(xhb + (size_t)NN * 128);    // N
    int*    rowptr = cnt + NN;                   // N+1
    int*    cursor = rowptr + NN + 1;            // N
    int*    blksum = cursor + NN;                // 128
    int*    colsrc = blksum + 128;               // NE

    float* n2vp = SA;
    float* agg  = SA;
    float* out  = (float*)d_out;

    const int BT = 256;
    dim3 b128(128), b256(BT);
    int eblk = (NE + BT - 1) / BT;
    int nblk = (NN + BT - 1) / BT;

    // ---- CSR ----
    hipMemsetAsync(cnt, 0, (size_t)NN * 4, stream);
    k_count<<<eblk, b256, 0, stream>>>(dst, cnt);
    k_scan1<<<SNBLK, b256, 0, stream>>>(cnt, rowptr, blksum);
    k_scan2<<<1, b128, 0, stream>>>(blksum);
    k_scan3<<<nblk, b256, 0, stream>>>(blksum, cnt, rowptr, cursor, invdeg);
    k_fill<<<eblk, b256, 0, stream>>>(src, dst, cursor, colsrc);

    // ---- front ----
    k_n2vp_t<<<NT, b256, 0, stream>>>(n2v, n2v_w, n2v_b, n2vp);
    k_front_t<<<NT, b256, 0, stream>>>(x, n2vp, ip_w, ip_b, gate_w, gate_b, S2, hb);

    // ---- SAGE 0: S2 -> S1 ----
    k_gather_mean<<<2048, b256, 0, stream>>>(rowptr, colsrc, invdeg, hb, agg);
    k_sage_t<<<NT, b256, 0, stream>>>(agg, S2, s0_wl, s0_bl, s0_wr, S1, hb);

    // ---- SAGE 1: S1 -> S2 ----
    k_gather_mean<<<2048, b256, 0, stream>>>(rowptr, colsrc, invdeg, hb, agg);
    k_sage_t<<<NT, b256, 0, stream>>>(agg, S1, s1_wl, s1_bl, s1_wr, S2, hb);

    // ---- GAT: S2 -> S1 ----
    k_gatxh_t<<<NT, b256, 0, stream>>>(S2, gat_w, att_s, att_d, xhb, a_s, a_d);
    k_gat_fused<<<2048, b256, 0, stream>>>(rowptr, colsrc, a_s, a_d, xhb, gat_b, S1);

    // ---- final SAGE: S1 -> out ----
    k_pfin<<<2048, b256, 0, stream>>>(S1, f_wl, Pb);
    k_final_fused<<<2048, b256, 0, stream>>>(rowptr, colsrc, invdeg, Pb, S1, f_bl, f_wr, out);
}